// Round 14
// baseline (336.453 us; speedup 1.0000x reference)
//
#include <hip/hip_runtime.h>
#include <cstdint>

// ---------------------------------------------------------------------------
// JanusCrossAttention: B=2,S=2048, Q_DIM=KV_DIM=2048, H=16, D=128, KVH=4
// I/O fp32; internals bf16 MFMA, fp32 accumulate.
// Pipeline (5 launches):
//   1. cvt_trans: q/kv f32->bf16 + wq/wk/wv transposes
//   2. gemm12: xq + xkv in one 768-block launch (3 blocks/CU, R12-proven),
//      per-head RMSNorm fused into the fp32-accumulator epilogue (R13)
//   3. post_merged: wo transpose + K/V fragment repack
//   4. attn: R6 structure FROZEN (~70 us, VGPR 52)
//   5. gemm3: out = ao @ woT — R14: retiled 64x128 -> 1024 blocks = 4/CU
//      (was 128x128 @ 512 blocks = 2/CU ~ 490 TF; R9/R10/R12 established
//      blocks/CU is THE lever for this GEMM structure; gemm12 at 3/CU runs
//      ~790 TF, near the m97-structure ceiling)
// ---------------------------------------------------------------------------

using bf16 = __bf16;
using bf16x4 = __attribute__((ext_vector_type(4))) __bf16;
using bf16x8 = __attribute__((ext_vector_type(8))) __bf16;
using s16x4  = __attribute__((ext_vector_type(4))) short;
using f32x4  = __attribute__((ext_vector_type(4))) float;

#define SEQ 2048
#define NH 16
#define NKVH 4
#define HD 128

// finite "minus infinity": avoids inf-inf NaNs in the split-K defer-max path
#define NEG (-3.0e38f)

// 16x16x16 bf16 MFMA (K=16) — C layout of a prior 16x16 MFMA feeds B directly.
#if defined(__has_builtin)
#if __has_builtin(__builtin_amdgcn_mfma_f32_16x16x16bf16_1k)
#define HAVE_1K 1
#endif
#endif
__device__ __forceinline__ f32x4 mfma_16x16x16(bf16x4 a, bf16x4 b, f32x4 c) {
#ifdef HAVE_1K
    return __builtin_amdgcn_mfma_f32_16x16x16bf16_1k(
        __builtin_bit_cast(s16x4, a), __builtin_bit_cast(s16x4, b), c, 0, 0, 0);
#else
    f32x4 d;
    asm volatile("v_mfma_f32_16x16x16_bf16 %0, %1, %2, %3"
                 : "=v"(d) : "v"(a), "v"(b), "v"(c));
    return d;
#endif
}

// native exp2 (v_exp_f32)
__device__ __forceinline__ float fast_exp2(float x) {
#if defined(__has_builtin)
#if __has_builtin(__builtin_amdgcn_exp2f)
    return __builtin_amdgcn_exp2f(x);
#else
    return exp2f(x);
#endif
#else
    return exp2f(x);
#endif
}

// async global->LDS, 16B per lane. LDS dest must be wave-uniform base + lane*16.
__device__ __forceinline__ void load_lds16(const bf16* g, bf16* l) {
    __builtin_amdgcn_global_load_lds(
        (const __attribute__((address_space(1))) unsigned int*)g,
        (__attribute__((address_space(3))) unsigned int*)l, 16, 0, 0);
}

// ---------------------------------------------------------------------------
// flat-thread 32x32 transpose tile body: in fp32 [R][C] -> out bf16 [C][R]
__device__ __forceinline__ void transpose_flat(const float* in, bf16* out,
                                               int R, int C, int bx, int by) {
    __shared__ bf16 tile[32][33];
    int tx = threadIdx.x & 31, ty = threadIdx.x >> 5;
    int x  = bx * 32 + tx;
    int y0 = by * 32 + ty;
#pragma unroll
    for (int i = 0; i < 32; i += 8) {
        int y = y0 + i;
        if (y < R && x < C) tile[ty + i][tx] = (bf16)in[(long)y * C + x];
    }
    __syncthreads();
    int ox  = by * 32 + tx;
    int oy0 = bx * 32 + ty;
#pragma unroll
    for (int i = 0; i < 32; i += 8) {
        int oy = oy0 + i;
        if (oy < C && ox < R) out[(long)oy * R + ox] = tile[tx][ty + i];
    }
}

// fused: blocks 0..8191 cvt q/kv f32->bf16; 8192..12287 transpose wq;
// 12288..13311 wk; 13312..14335 wv.
__global__ __launch_bounds__(256) void cvt_trans(const float* __restrict__ q,
                                                 const float* __restrict__ kv,
                                                 bf16* __restrict__ oq,
                                                 bf16* __restrict__ okv,
                                                 const float* __restrict__ wq,
                                                 const float* __restrict__ wk,
                                                 const float* __restrict__ wv,
                                                 bf16* __restrict__ wqT,
                                                 bf16* __restrict__ wkvT) {
    int bid = blockIdx.x;
    if (bid < 8192) {
        int i = bid * 256 + threadIdx.x;
        const float* in;
        bf16* out;
        int j;
        if (i < 1048576) { in = q;  out = oq;  j = i; }
        else             { in = kv; out = okv; j = i - 1048576; }
        const float4* p = (const float4*)in + (long)j * 2;
        float4 f0 = p[0], f1 = p[1];
        bf16x8 o = {(bf16)f0.x, (bf16)f0.y, (bf16)f0.z, (bf16)f0.w,
                    (bf16)f1.x, (bf16)f1.y, (bf16)f1.z, (bf16)f1.w};
        *((bf16x8*)out + j) = o;
    } else if (bid < 12288) {
        int t = bid - 8192;
        transpose_flat(wq, wqT, 2048, 2048, t & 63, t >> 6);
    } else if (bid < 13312) {
        int t = bid - 12288;
        transpose_flat(wk, wkvT, 2048, 512, t & 15, t >> 4);
    } else {
        int t = bid - 13312;
        transpose_flat(wv, wkvT + 512L * 2048, 2048, 512, t & 15, t >> 4);
    }
}

// ---------------------------------------------------------------------------
// Shared GEMM block body: C 128x128 tile at (m0,n0), A[MxK] @ BT[NxK]^T,
// bf16 in, fp32 acc, CT out. Double-buffered global_load_lds staging
// (R9 config — measured best). If NORM: per-head RMSNorm on the fp32
// accumulator before the store (R13; each 128-col tile == one head).
template <typename CT, bool NORM>
__device__ __forceinline__ void gemm_block(const bf16* A, const bf16* BT, CT* C,
                                           int N, int K, int m0, int n0,
                                           bf16 (*As)[128][32], bf16 (*Bs)[128][32],
                                           const float* Wn) {
    const int tid  = threadIdx.x;
    const int wave = tid >> 6, lane = tid & 63;
    const int wm = (wave >> 1) * 64, wn = (wave & 1) * 64;
    const int lrow = lane & 15, quad = lane >> 4;
    const int lko = quad * 8;

    const bf16* ga0 = A  + (long)(m0 + (tid >> 2)) * K + (tid & 3) * 8;
    const bf16* ga1 = ga0 + 64L * K;
    const bf16* gb0 = BT + (long)(n0 + (tid >> 2)) * K + (tid & 3) * 8;
    const bf16* gb1 = gb0 + 64L * K;
    bf16* la0 = &As[0][0][0] + tid * 8;
    bf16* lb0 = &Bs[0][0][0] + tid * 8;

    f32x4 acc[4][4] = {};

    const int nIt = K >> 5;
    load_lds16(ga0, la0);
    load_lds16(ga1, la0 + 2048);
    load_lds16(gb0, lb0);
    load_lds16(gb1, lb0 + 2048);
    __syncthreads();

#pragma unroll 1
    for (int it = 0; it < nIt; ++it) {
        const int cur = it & 1;
        if (it + 1 < nIt) {
            const int k0 = (it + 1) * 32;
            bf16* la = la0 + (cur ^ 1) * 4096;
            bf16* lb = lb0 + (cur ^ 1) * 4096;
            load_lds16(ga0 + k0, la);
            load_lds16(ga1 + k0, la + 2048);
            load_lds16(gb0 + k0, lb);
            load_lds16(gb1 + k0, lb + 2048);
        }
        bf16x8 af[4], bfr[4];
#pragma unroll
        for (int i = 0; i < 4; ++i) af[i]  = *(const bf16x8*)(&As[cur][wm + i * 16 + lrow][lko]);
#pragma unroll
        for (int j = 0; j < 4; ++j) bfr[j] = *(const bf16x8*)(&Bs[cur][wn + j * 16 + lrow][lko]);
#pragma unroll
        for (int i = 0; i < 4; ++i)
#pragma unroll
            for (int j = 0; j < 4; ++j)
                acc[i][j] = __builtin_amdgcn_mfma_f32_16x16x32_bf16(af[i], bfr[j], acc[i][j], 0, 0, 0);
        __syncthreads();
    }

    if constexpr (NORM) {
        float* ssb = (float*)&As[0][0][0];   // [2][128] f32 scratch (1 KB)
#pragma unroll
        for (int i = 0; i < 4; ++i)
#pragma unroll
            for (int r = 0; r < 4; ++r) {
                float p = 0.f;
#pragma unroll
                for (int j = 0; j < 4; ++j) p += acc[i][j][r] * acc[i][j][r];
                p += __shfl_xor(p, 1, 64);
                p += __shfl_xor(p, 2, 64);
                p += __shfl_xor(p, 4, 64);
                p += __shfl_xor(p, 8, 64);
                if (lrow == 0) ssb[(wave & 1) * 128 + wm + i * 16 + quad * 4 + r] = p;
            }
        __syncthreads();
        float wgt[4];
#pragma unroll
        for (int j = 0; j < 4; ++j) wgt[j] = Wn[wn + j * 16 + lrow];
#pragma unroll
        for (int i = 0; i < 4; ++i) {
            const int row0 = wm + i * 16 + quad * 4;
#pragma unroll
            for (int r = 0; r < 4; ++r) {
                float tot = ssb[row0 + r] + ssb[128 + row0 + r];
                float rsc = rsqrtf(tot * (1.0f / 128.0f) + 1e-5f);
#pragma unroll
                for (int j = 0; j < 4; ++j) acc[i][j][r] *= rsc * wgt[j];
            }
        }
    }

#pragma unroll
    for (int i = 0; i < 4; ++i) {
        int mrow0 = m0 + wm + i * 16 + quad * 4;
#pragma unroll
        for (int j = 0; j < 4; ++j) {
            int ncol = n0 + wn + j * 16 + lrow;
#pragma unroll
            for (int r = 0; r < 4; ++r)
                C[(long)(mrow0 + r) * N + ncol] = (CT)acc[i][j][r];
        }
    }
}

// Fused gemm1+gemm2 with in-epilogue RMSNorm.
// blocks 0..511: xq = sb @ wqT^T (N=2048), norm with qnw (all 16 heads);
// blocks 512..767: xkv = sbKV @ wkvT^T (N=1024): n0<512 -> K head, norm with
// knw; n0>=512 -> V, no norm. 768 blocks = exactly 3/CU, co-resident.
__global__ __launch_bounds__(256) void gemm12(const bf16* __restrict__ A1,
                                              const bf16* __restrict__ B1,
                                              bf16* __restrict__ C1,
                                              const bf16* __restrict__ A2,
                                              const bf16* __restrict__ B2,
                                              bf16* __restrict__ C2,
                                              const float* __restrict__ qnw,
                                              const float* __restrict__ knw) {
    __shared__ bf16 As[2][128][32];
    __shared__ bf16 Bs[2][128][32];
    const int bid = blockIdx.x;
    if (bid < 512) {
        const int swz = (bid & 7) * 64 + (bid >> 3);
        const int bx = swz % 16, by = swz / 16;
        gemm_block<bf16, true>(A1, B1, C1, 2048, 2048, by * 128, bx * 128, As, Bs, qnw);
    } else {
        const int sub = bid - 512;
        const int swz = (sub & 7) * 32 + (sub >> 3);
        const int bx = swz % 8, by = swz / 8;
        const int n0 = bx * 128;
        if (n0 < 512)
            gemm_block<bf16, true>(A2, B2, C2, 1024, 2048, by * 128, n0, As, Bs, knw);
        else
            gemm_block<bf16, false>(A2, B2, C2, 1024, 2048, by * 128, n0, As, Bs, nullptr);
    }
}

// ---------------------------------------------------------------------------
// gemm3: out(f32)[4096][2048] = ao @ woT^T, 64x128 tiles -> grid 16x64 =
// 1024 blocks = exactly 4 blocks/CU (R14). LDS 24 KB/block; acc 32 f32/lane.
// As 64x32 staged in ONE 16B/thread pass; Bs 128x32 in two. XCD swizzle.
__global__ __launch_bounds__(256) void gemm3_64(const bf16* __restrict__ A,
                                                const bf16* __restrict__ BT,
                                                float* __restrict__ C) {
    __shared__ bf16 As[2][64][32];
    __shared__ bf16 Bs[2][128][32];
    const int N = 2048, K = 2048;
    const int tid  = threadIdx.x;
    const int wave = tid >> 6, lane = tid & 63;
    const int bid = blockIdx.y * gridDim.x + blockIdx.x;
    const int swz = (bid & 7) * 128 + (bid >> 3);
    const int bx = swz % 16, by = swz / 16;
    const int m0 = by * 64, n0 = bx * 128;
    const int wm = (wave >> 1) * 32, wn = (wave & 1) * 64;
    const int lrow = lane & 15, quad = lane >> 4;
    const int lko = quad * 8;

    const bf16* ga0 = A  + (long)(m0 + (tid >> 2)) * K + (tid & 3) * 8;
    const bf16* gb0 = BT + (long)(n0 + (tid >> 2)) * K + (tid & 3) * 8;
    const bf16* gb1 = gb0 + 64L * K;
    bf16* la0 = &As[0][0][0] + tid * 8;
    bf16* lb0 = &Bs[0][0][0] + tid * 8;

    f32x4 acc[2][4] = {};

    const int nIt = K >> 5;
    load_lds16(ga0, la0);
    load_lds16(gb0, lb0);
    load_lds16(gb1, lb0 + 2048);
    __syncthreads();

#pragma unroll 1
    for (int it = 0; it < nIt; ++it) {
        const int cur = it & 1;
        if (it + 1 < nIt) {
            const int k0 = (it + 1) * 32;
            bf16* la = la0 + (cur ^ 1) * 2048;
            bf16* lb = lb0 + (cur ^ 1) * 4096;
            load_lds16(ga0 + k0, la);
            load_lds16(gb0 + k0, lb);
            load_lds16(gb1 + k0, lb + 2048);
        }
        bf16x8 af[2], bfr[4];
#pragma unroll
        for (int i = 0; i < 2; ++i) af[i]  = *(const bf16x8*)(&As[cur][wm + i * 16 + lrow][lko]);
#pragma unroll
        for (int j = 0; j < 4; ++j) bfr[j] = *(const bf16x8*)(&Bs[cur][wn + j * 16 + lrow][lko]);
#pragma unroll
        for (int i = 0; i < 2; ++i)
#pragma unroll
            for (int j = 0; j < 4; ++j)
                acc[i][j] = __builtin_amdgcn_mfma_f32_16x16x32_bf16(af[i], bfr[j], acc[i][j], 0, 0, 0);
        __syncthreads();
    }
#pragma unroll
    for (int i = 0; i < 2; ++i) {
        int mrow0 = m0 + wm + i * 16 + quad * 4;
#pragma unroll
        for (int j = 0; j < 4; ++j) {
            int ncol = n0 + wn + j * 16 + lrow;
#pragma unroll
            for (int r = 0; r < 4; ++r)
                C[(long)(mrow0 + r) * N + ncol] = acc[i][j][r];
        }
    }
}

// ---------------------------------------------------------------------------
// post_merged: blocks 0..4095 transpose wo -> woT (into wqT buffer, free
// after gemm12); blocks 4096..4351 repack K and V^T (xkv already normed).
__global__ __launch_bounds__(256) void post_merged(const float* __restrict__ wo,
                                                   bf16* __restrict__ woT,
                                                   const bf16* __restrict__ xkv,
                                                   bf16* __restrict__ kf,
                                                   bf16* __restrict__ vf) {
    __shared__ bf16 Vls[64][136];
    int bid = blockIdx.x;
    if (bid < 4096) {
        transpose_flat(wo, woT, 2048, 2048, bid & 63, bid >> 6);
        return;
    }
    int rb = bid - 4096;               // 0..255
    int kt = rb & 31, kvh = (rb >> 5) & 3, b = rb >> 7;
    int tid = threadIdx.x, lane = tid & 63;
    int lrow = lane & 15, quad = lane >> 4;

    // ---- K part (no LDS) ----
    {
        int ks = tid >> 6;
        const bf16* src = xkv + ((long)b * SEQ + kt * 64) * 1024 + kvh * HD;
        bf16* dst = kf + ((long)((b * NKVH + kvh) * 32 + kt)) * 8192;
#pragma unroll
        for (int nt = 0; nt < 4; ++nt) {
            bf16x8 v = *(const bf16x8*)(src + (long)(nt * 16 + lrow) * 1024 + ks * 32 + quad * 8);
            *(bf16x8*)(dst + ((nt * 4 + ks) * 64 + lane) * 8) = v;
        }
    }

    // ---- V part (transpose via LDS) ----
    {
        const bf16* src = xkv + ((long)b * SEQ + kt * 64) * 1024 + 512 + kvh * HD;
#pragma unroll
        for (int p = 0; p < 4; ++p) {
            int c = p * 256 + tid;
            int r = c >> 4, dc = (c & 15) * 8;
            *(uint4*)(&Vls[r][dc]) = *(const uint4*)(src + (long)r * 1024 + dc);
        }
        __syncthreads();
        int w = tid >> 6;
        bf16* dst = vf + ((long)((b * NKVH + kvh) * 32 + kt)) * 8192;
#pragma unroll
        for (int nt = 0; nt < 4; ++nt)
#pragma unroll
            for (int dtl = 0; dtl < 2; ++dtl) {
                int dt = w * 2 + dtl;
                bf16x4 v = {Vls[nt * 16 + quad * 4 + 0][dt * 16 + lrow],
                            Vls[nt * 16 + quad * 4 + 1][dt * 16 + lrow],
                            Vls[nt * 16 + quad * 4 + 2][dt * 16 + lrow],
                            Vls[nt * 16 + quad * 4 + 3][dt * 16 + lrow]};
                *(bf16x4*)(dst + ((nt * 8 + dt) * 64 + lane) * 4) = v;
            }
    }
}

// ---------------------------------------------------------------------------
// Flash attention: R6 structure FROZEN (best measured: ~70 us, VGPR 52).
__global__ __launch_bounds__(512, 4) void attn_kernel(const bf16* __restrict__ Q,
                                                      const bf16* __restrict__ KF,
                                                      const bf16* __restrict__ VF,
                                                      bf16* __restrict__ O) {
    __shared__ bf16 Kf[2][8192];   // [buf][half(2)·nt(2)·ks(4)·512] — 32 KB
    __shared__ bf16 Vf[2][8192];   // [buf][half(2)·nt(2)·dt(8)·256] — 32 KB
    const int tid = threadIdx.x, wave = tid >> 6, lane = tid & 63;
    const int w4 = wave & 3, grpW = wave >> 2;
    const int bid = blockIdx.x;
    const int grp = bid & 7;                  // -> XCD via bid%8 round-robin
    const int b = grp >> 2, kvh = grp & 3;
    const int slot = bid >> 3;                // 0..63
    const int pr = slot & 15;
    const int h = kvh * 4 + (slot >> 4);
    const int lrow = lane & 15, quad = lane >> 4;
    const float scl2 = 0.12751744f;     // (1/sqrt(128)) * log2(e)
    const float THR = 62.7f;            // ~8 ln-units in raw-score domain

    const int qt1 = 31 - pr, qt2 = pr;

    const bf16* kfb = KF + ((long)(b * NKVH + kvh) * 32) * 8192;
    const bf16* vfb = VF + ((long)(b * NKVH + kvh) * 32) * 8192;

    auto stage = [&](int pair, int bsel) {
        const bf16* kg = kfb + (long)pair * 8192 + tid * 8;
        const bf16* vg = vfb + (long)pair * 8192 + tid * 8;
        bf16* kd = &Kf[bsel][0] + tid * 8;
        bf16* vd = &Vf[bsel][0] + tid * 8;
        load_lds16(kg, kd);
        load_lds16(kg + 4096, kd + 4096);
        load_lds16(vg, vd);
        load_lds16(vg + 4096, vd + 4096);
    };

    float m_i = NEG, l_i = 0.f;
    f32x4 oT[8] = {};   // out^T: d = dt*16 + quad*4 + r, q = lane&15
    bf16x8 bqw[4];

    auto combine_write_reset = [&](int qrow) {
        float a1keep = 0.f;
        float* vs = (float*)&Vf[0][0];
        const int sl = w4 * 64 + lane;
        __syncthreads();
        if (grpW == 1) {
            float* d = vs + sl * 18;
#pragma unroll
            for (int dt = 0; dt < 4; ++dt)
#pragma unroll
                for (int r = 0; r < 4; ++r) d[dt * 4 + r] = oT[dt][r];
            d[16] = m_i; d[17] = l_i;
        }
        __syncthreads();
        if (grpW == 0) {
            const float* s = vs + sl * 18;
            float m1 = s[16], l1 = s[17];
            float ms = fmaxf(m_i, m1);
            float a0 = fast_exp2((m_i - ms) * scl2);
            float a1 = fast_exp2((m1 - ms) * scl2);
            a1keep = a1;
            l_i = a0 * l_i + a1 * l1;
#pragma unroll
            for (int dt = 0; dt < 4; ++dt)
#pragma unroll
                for (int r = 0; r < 4; ++r)
                    oT[dt][r] = a0 * oT[dt][r] + a1 * s[dt * 4 + r];
#pragma unroll
            for (int dt = 4; dt < 8; ++dt)
#pragma unroll
                for (int r = 0; r < 4; ++r) oT[dt][r] *= a0;
            m_i = ms;
        }
        __syncthreads();
        if (grpW == 1) {
            float* d = vs + sl * 16;
#pragma unroll
            for (int dt = 4; dt < 8; ++dt)
#pragma unroll
                for (int r = 0; r < 4; ++r) d[(dt - 4) * 4 + r] = oT[dt][r];
        }
        __syncthreads();
        if (grpW == 0) {
            const float* s = vs + sl * 16;
#pragma unroll
            for (int dt = 4; dt < 8; ++dt)
#pragma unroll
                for (int r = 0; r < 4; ++r) oT[dt][r] += a1keep * s[(dt - 4) * 4 + r];
            float inv_l = 1.0f / l_i;
            bf16* obase = O + ((long)(b * SEQ + qrow)) * (NH * HD) + h * HD;
#pragma unroll
            for (int dt = 0; dt < 8; ++dt) {
                bf16x4 o = {(bf16)(oT[dt][0] * inv_l), (bf16)(oT[dt][1] * inv_l),
                            (bf16)(oT[dt][2] * inv_l), (bf16)(oT[dt][3] * inv_l)};
                *(bf16x4*)(obase + dt * 16 + quad * 4) = o;
            }
        }
        __syncthreads();   // scratch/LDS free for restage
        m_i = NEG; l_i = 0.f;
#pragma unroll
        for (int dt = 0; dt < 8; ++dt)
#pragma unroll
            for (int r = 0; r < 4; ++r) oT[dt][r] = 0.f;
    };

    auto process = [&](int i, int itN, int myq, int cur) {
        const int kbg = 2 * i + grpW;
        const bool diag = (i == itN - 1);
        const bf16* kbase = &Kf[cur][0] + grpW * 4096;
        const bf16* vbase = &Vf[cur][0] + grpW * 4096;

        f32x4 st[2];
        __builtin_amdgcn_s_setprio(1);
#pragma unroll
        for (int nt = 0; nt < 2; ++nt) {
            f32x4 acc = {};
#pragma unroll
            for (int ks = 0; ks < 4; ++ks) {
                bf16x8 ak = *(const bf16x8*)(kbase + (nt * 4 + ks) * 512 + lane * 8);
                acc = __builtin_amdgcn_mfma_f32_16x16x32_bf16(ak, bqw[ks], acc, 0, 0, 0);
            }
            st[nt] = acc;
        }
        __builtin_amdgcn_s_setprio(0);
        if (diag) {
#pragma unroll
            for (int nt = 0; nt < 2; ++nt) {
                int kp0 = kbg * 32 + nt * 16 + quad * 4;
#pragma unroll
                for (int r = 0; r < 4; ++r)
                    if (kp0 + r > myq) st[nt][r] = NEG;
            }
        }

        float mx = st[0][0];
#pragma unroll
        for (int nt = 0; nt < 2; ++nt)
#pragma unroll
            for (int r = 0; r < 4; ++r) mx = fmaxf(mx, st[nt][r]);
        mx = fmaxf(mx, __shfl_xor(mx, 16, 64));
        mx = fmaxf(mx, __shfl_xor(mx, 32, 64));

        if (!__all(mx - m_i <= THR)) {
            float mnew = fmaxf(m_i, mx);
            float alpha = fast_exp2((m_i - mnew) * scl2);
            l_i *= alpha;
#pragma unroll
            for (int dt = 0; dt < 8; ++dt)
#pragma unroll
                for (int r = 0; r < 4; ++r) oT[dt][r] *= alpha;
            m_i = mnew;
        }
        float rs = 0.f;
#pragma unroll
        for (int nt = 0; nt < 2; ++nt)
#pragma unroll
            for (int r = 0; r < 4; ++r) {
                float p = fast_exp2((st[nt][r] - m_i) * scl2);
                st[nt][r] = p;
                rs += p;
            }
        rs += __shfl_xor(rs, 16, 64);
        rs += __shfl_xor(rs, 32, 64);
        l_i += rs;

        bf16x4 pf[2];
#pragma unroll
        for (int nt = 0; nt < 2; ++nt) {
            bf16x4 tt = {(bf16)st[nt][0], (bf16)st[nt][1],
                         (bf16)st[nt][2], (bf16)st[nt][3]};
            pf[nt] = tt;
        }

        __builtin_amdgcn_s_setprio(1);
#pragma unroll
        for (int nt = 0; nt < 2; ++nt)
#pragma unroll
            for (int dt = 0; dt < 8; ++dt) {
                bf16x4 av = *(const bf16x4*)(vbase + (nt * 8 + dt) * 256 + lane * 4);
                oT[dt] = mfma_16x16x16(av, pf[nt], oT[dt]);
            }
        __builtin_amdgcn_s_setprio(0);
    };

    // ---- tile 1: qt1, it1 = qt1+1 staged pairs --------------------------
    const int it1 = qt1 + 1;
    const int myq1 = qt1 * 64 + w4 * 16 + lrow;
    {
        const bf16* qrow = Q + ((long)(b * SEQ + myq1)) * (NH * HD) + h * HD;
#pragma unroll
        for (int ks = 0; ks < 4; ++ks)
            bqw[ks] = *(const bf16x8*)(qrow + ks * 32 + quad * 8);
    }
    stage(0, 0);
    __syncthreads();
#pragma unroll 1
    for (int i = 0; i < it1; ++i) {
        const int cur = i & 1;
        if (i + 1 < it1) stage(i + 1, cur ^ 1);
        process(i, it1, myq1, cur);
        __syncthreads();
    }
    combine_write_reset(myq1);

    // ---- tile 2: qt2, it2 = qt2+1 staged pairs --------------------------
    const int it2 = qt2 + 1;
    const int myq2 = qt2 * 64 + w4 * 16 + lrow;
    {
        const bf16* qrow = Q + ((long)(b * SEQ + myq2)) * (NH * HD) + h * HD;
#pragma unroll
        for (int ks = 0; ks < 4; ++ks)
            bqw[ks] = *(const bf16x8*)(qrow + ks * 32 + quad * 8);
    }
    stage(0, 0);
    __syncthreads();
#pragma unroll 1
    for (int i = 0; i < it2; ++i) {
        const int cur = i & 1;
        if (i + 1 < it2) stage(i + 1, cur ^ 1);
        process(i, it2, myq2, cur);
        __syncthreads();
    }
    combine_write_reset(myq2);
}

// ---------------------------------------------------------------------------
extern "C" void kernel_launch(void* const* d_in, const int* in_sizes, int n_in,
                              void* d_out, int out_size, void* d_ws, size_t ws_size,
                              hipStream_t stream) {
    const float* q_stream  = (const float*)d_in[0];
    const float* kv_stream = (const float*)d_in[1];
    const float* wq  = (const float*)d_in[2];
    const float* wk  = (const float*)d_in[3];
    const float* wv  = (const float*)d_in[4];
    const float* wo  = (const float*)d_in[5];
    const float* qnw = (const float*)d_in[6];
    const float* knw = (const float*)d_in[7];
    float* out = (float*)d_out;

    // workspace (bf16 elems), total 30M elems = 60MB
    bf16* ws   = (bf16*)d_ws;
    bf16* sb   = ws;                        // 8M: q bf16, later attn out
    bf16* wqT  = ws + 8L * 1024 * 1024;     // 4M: wq^T, later wo^T
    bf16* wkvT = wqT + 4L * 1024 * 1024;    // 2M: [wk^T ; wv^T] = [1024][2048]
    bf16* xq   = wkvT + 2L * 1024 * 1024;   // 8M: [4096][2048]
    bf16* xkv  = xq + 8L * 1024 * 1024;     // 4M: [4096][1024] = [K | V]
    bf16* kf   = xkv + 4L * 1024 * 1024;    // 2M: K fragment-major
    bf16* vf   = kf + 2L * 1024 * 1024;     // 2M: V^T fragment-major
    // kv bf16 staging lives in d_out (32 MB f32 >= 8 MB needed); the final
    // GEMM fully overwrites out, so scratch use is safe.
    bf16* sbKV = (bf16*)d_out;

    cvt_trans<<<14336, 256, 0, stream>>>(q_stream, kv_stream, sb, sbKV,
                                         wq, wk, wv, wqT, wkvT);
    gemm12<<<768, 256, 0, stream>>>(sb, wqT, xq, sbKV, wkvT, xkv, qnw, knw);
    post_merged<<<4352, 256, 0, stream>>>(wo, wqT, xkv, kf, vf);
    attn_kernel<<<dim3(512), dim3(512), 0, stream>>>(xq, kf, vf, sb);
    gemm3_64<<<dim3(16, 64), 256, 0, stream>>>(sb, wqT, out);

    (void)in_sizes; (void)n_in; (void)out_size; (void)ws_size;
}

// Round 15
// 333.264 us; speedup vs baseline: 1.0096x; 1.0096x over previous
//
#include <hip/hip_runtime.h>
#include <cstdint>

// ---------------------------------------------------------------------------
// JanusCrossAttention: B=2,S=2048, Q_DIM=KV_DIM=2048, H=16, D=128, KVH=4
// I/O fp32; internals bf16 MFMA, fp32 accumulate.
// Pipeline (5 launches):
//   1. cvt_trans: q/kv f32->bf16 + wq/wk/wv transposes
//   2. gemm12: xq + xkv in one 768-block launch (3 blocks/CU, R12-proven),
//      per-head RMSNorm fused into the fp32-accumulator epilogue (R13).
//      R15: square 8x8 per-XCD tile chunks (was row-chunks: each XCD pulled
//      ALL B panels -> FETCH 65.7 MB vs 36 ideal).
//   3. post_merged: wo transpose + K/V fragment repack
//   4. attn: R6 structure FROZEN (~70 us, VGPR 52)
//   5. gemm3: 128x128 @ 512 blocks (R13 config RESTORED — R14's 64x128
//      retile to 4/CU regressed: 32 MFMA/barrier halved per-block efficiency;
//      blocks/CU lever saturates at 3 with 128^2 tiles). Square XCD chunks.
// ---------------------------------------------------------------------------

using bf16 = __bf16;
using bf16x4 = __attribute__((ext_vector_type(4))) __bf16;
using bf16x8 = __attribute__((ext_vector_type(8))) __bf16;
using s16x4  = __attribute__((ext_vector_type(4))) short;
using f32x4  = __attribute__((ext_vector_type(4))) float;

#define SEQ 2048
#define NH 16
#define NKVH 4
#define HD 128

// finite "minus infinity": avoids inf-inf NaNs in the split-K defer-max path
#define NEG (-3.0e38f)

// 16x16x16 bf16 MFMA (K=16) — C layout of a prior 16x16 MFMA feeds B directly.
#if defined(__has_builtin)
#if __has_builtin(__builtin_amdgcn_mfma_f32_16x16x16bf16_1k)
#define HAVE_1K 1
#endif
#endif
__device__ __forceinline__ f32x4 mfma_16x16x16(bf16x4 a, bf16x4 b, f32x4 c) {
#ifdef HAVE_1K
    return __builtin_amdgcn_mfma_f32_16x16x16bf16_1k(
        __builtin_bit_cast(s16x4, a), __builtin_bit_cast(s16x4, b), c, 0, 0, 0);
#else
    f32x4 d;
    asm volatile("v_mfma_f32_16x16x16_bf16 %0, %1, %2, %3"
                 : "=v"(d) : "v"(a), "v"(b), "v"(c));
    return d;
#endif
}

// native exp2 (v_exp_f32)
__device__ __forceinline__ float fast_exp2(float x) {
#if defined(__has_builtin)
#if __has_builtin(__builtin_amdgcn_exp2f)
    return __builtin_amdgcn_exp2f(x);
#else
    return exp2f(x);
#endif
#else
    return exp2f(x);
#endif
}

// async global->LDS, 16B per lane. LDS dest must be wave-uniform base + lane*16.
__device__ __forceinline__ void load_lds16(const bf16* g, bf16* l) {
    __builtin_amdgcn_global_load_lds(
        (const __attribute__((address_space(1))) unsigned int*)g,
        (__attribute__((address_space(3))) unsigned int*)l, 16, 0, 0);
}

// ---------------------------------------------------------------------------
// flat-thread 32x32 transpose tile body: in fp32 [R][C] -> out bf16 [C][R]
__device__ __forceinline__ void transpose_flat(const float* in, bf16* out,
                                               int R, int C, int bx, int by) {
    __shared__ bf16 tile[32][33];
    int tx = threadIdx.x & 31, ty = threadIdx.x >> 5;
    int x  = bx * 32 + tx;
    int y0 = by * 32 + ty;
#pragma unroll
    for (int i = 0; i < 32; i += 8) {
        int y = y0 + i;
        if (y < R && x < C) tile[ty + i][tx] = (bf16)in[(long)y * C + x];
    }
    __syncthreads();
    int ox  = by * 32 + tx;
    int oy0 = bx * 32 + ty;
#pragma unroll
    for (int i = 0; i < 32; i += 8) {
        int oy = oy0 + i;
        if (oy < C && ox < R) out[(long)oy * R + ox] = tile[tx][ty + i];
    }
}

// fused: blocks 0..8191 cvt q/kv f32->bf16; 8192..12287 transpose wq;
// 12288..13311 wk; 13312..14335 wv.
__global__ __launch_bounds__(256) void cvt_trans(const float* __restrict__ q,
                                                 const float* __restrict__ kv,
                                                 bf16* __restrict__ oq,
                                                 bf16* __restrict__ okv,
                                                 const float* __restrict__ wq,
                                                 const float* __restrict__ wk,
                                                 const float* __restrict__ wv,
                                                 bf16* __restrict__ wqT,
                                                 bf16* __restrict__ wkvT) {
    int bid = blockIdx.x;
    if (bid < 8192) {
        int i = bid * 256 + threadIdx.x;
        const float* in;
        bf16* out;
        int j;
        if (i < 1048576) { in = q;  out = oq;  j = i; }
        else             { in = kv; out = okv; j = i - 1048576; }
        const float4* p = (const float4*)in + (long)j * 2;
        float4 f0 = p[0], f1 = p[1];
        bf16x8 o = {(bf16)f0.x, (bf16)f0.y, (bf16)f0.z, (bf16)f0.w,
                    (bf16)f1.x, (bf16)f1.y, (bf16)f1.z, (bf16)f1.w};
        *((bf16x8*)out + j) = o;
    } else if (bid < 12288) {
        int t = bid - 8192;
        transpose_flat(wq, wqT, 2048, 2048, t & 63, t >> 6);
    } else if (bid < 13312) {
        int t = bid - 12288;
        transpose_flat(wk, wkvT, 2048, 512, t & 15, t >> 4);
    } else {
        int t = bid - 13312;
        transpose_flat(wv, wkvT + 512L * 2048, 2048, 512, t & 15, t >> 4);
    }
}

// ---------------------------------------------------------------------------
// Shared GEMM block body: C 128x128 tile at (m0,n0), A[MxK] @ BT[NxK]^T,
// bf16 in, fp32 acc, CT out. Double-buffered global_load_lds staging
// (R9 config — measured best). If NORM: per-head RMSNorm on the fp32
// accumulator before the store (R13; each 128-col tile == one head).
template <typename CT, bool NORM>
__device__ __forceinline__ void gemm_block(const bf16* A, const bf16* BT, CT* C,
                                           int N, int K, int m0, int n0,
                                           bf16 (*As)[128][32], bf16 (*Bs)[128][32],
                                           const float* Wn) {
    const int tid  = threadIdx.x;
    const int wave = tid >> 6, lane = tid & 63;
    const int wm = (wave >> 1) * 64, wn = (wave & 1) * 64;
    const int lrow = lane & 15, quad = lane >> 4;
    const int lko = quad * 8;

    const bf16* ga0 = A  + (long)(m0 + (tid >> 2)) * K + (tid & 3) * 8;
    const bf16* ga1 = ga0 + 64L * K;
    const bf16* gb0 = BT + (long)(n0 + (tid >> 2)) * K + (tid & 3) * 8;
    const bf16* gb1 = gb0 + 64L * K;
    bf16* la0 = &As[0][0][0] + tid * 8;
    bf16* lb0 = &Bs[0][0][0] + tid * 8;

    f32x4 acc[4][4] = {};

    const int nIt = K >> 5;
    load_lds16(ga0, la0);
    load_lds16(ga1, la0 + 2048);
    load_lds16(gb0, lb0);
    load_lds16(gb1, lb0 + 2048);
    __syncthreads();

#pragma unroll 1
    for (int it = 0; it < nIt; ++it) {
        const int cur = it & 1;
        if (it + 1 < nIt) {
            const int k0 = (it + 1) * 32;
            bf16* la = la0 + (cur ^ 1) * 4096;
            bf16* lb = lb0 + (cur ^ 1) * 4096;
            load_lds16(ga0 + k0, la);
            load_lds16(ga1 + k0, la + 2048);
            load_lds16(gb0 + k0, lb);
            load_lds16(gb1 + k0, lb + 2048);
        }
        bf16x8 af[4], bfr[4];
#pragma unroll
        for (int i = 0; i < 4; ++i) af[i]  = *(const bf16x8*)(&As[cur][wm + i * 16 + lrow][lko]);
#pragma unroll
        for (int j = 0; j < 4; ++j) bfr[j] = *(const bf16x8*)(&Bs[cur][wn + j * 16 + lrow][lko]);
#pragma unroll
        for (int i = 0; i < 4; ++i)
#pragma unroll
            for (int j = 0; j < 4; ++j)
                acc[i][j] = __builtin_amdgcn_mfma_f32_16x16x32_bf16(af[i], bfr[j], acc[i][j], 0, 0, 0);
        __syncthreads();
    }

    if constexpr (NORM) {
        float* ssb = (float*)&As[0][0][0];   // [2][128] f32 scratch (1 KB)
#pragma unroll
        for (int i = 0; i < 4; ++i)
#pragma unroll
            for (int r = 0; r < 4; ++r) {
                float p = 0.f;
#pragma unroll
                for (int j = 0; j < 4; ++j) p += acc[i][j][r] * acc[i][j][r];
                p += __shfl_xor(p, 1, 64);
                p += __shfl_xor(p, 2, 64);
                p += __shfl_xor(p, 4, 64);
                p += __shfl_xor(p, 8, 64);
                if (lrow == 0) ssb[(wave & 1) * 128 + wm + i * 16 + quad * 4 + r] = p;
            }
        __syncthreads();
        float wgt[4];
#pragma unroll
        for (int j = 0; j < 4; ++j) wgt[j] = Wn[wn + j * 16 + lrow];
#pragma unroll
        for (int i = 0; i < 4; ++i) {
            const int row0 = wm + i * 16 + quad * 4;
#pragma unroll
            for (int r = 0; r < 4; ++r) {
                float tot = ssb[row0 + r] + ssb[128 + row0 + r];
                float rsc = rsqrtf(tot * (1.0f / 128.0f) + 1e-5f);
#pragma unroll
                for (int j = 0; j < 4; ++j) acc[i][j][r] *= rsc * wgt[j];
            }
        }
    }

#pragma unroll
    for (int i = 0; i < 4; ++i) {
        int mrow0 = m0 + wm + i * 16 + quad * 4;
#pragma unroll
        for (int j = 0; j < 4; ++j) {
            int ncol = n0 + wn + j * 16 + lrow;
#pragma unroll
            for (int r = 0; r < 4; ++r)
                C[(long)(mrow0 + r) * N + ncol] = (CT)acc[i][j][r];
        }
    }
}

// gemm3: out(f32) = ao @ woT^T, 128x128 tiles, 512 blocks (R13 config).
// R15: square 8x8 per-XCD chunk — XCD x owns bx in [8(x&1),+8), by in
// [8(x>>1),+8) of the 16x32 tile grid (4 MB A + 4 MB B per XCD, balanced).
__global__ __launch_bounds__(256) void gemm3_bt(const bf16* __restrict__ A,
                                                const bf16* __restrict__ BT,
                                                float* __restrict__ C) {
    __shared__ bf16 As[2][128][32];
    __shared__ bf16 Bs[2][128][32];
    const int bid = blockIdx.x;
    const int x = bid & 7, c = bid >> 3;         // XCD, chunk id 0..63
    const int bx = ((x & 1) << 3) + (c & 7);
    const int by = ((x >> 1) << 3) + (c >> 3);
    gemm_block<float, false>(A, BT, C, 2048, 2048, by * 128, bx * 128, As, Bs, nullptr);
}

// Fused gemm1+gemm2 with in-epilogue RMSNorm.
// blocks 0..511: xq = sb @ wqT^T (N=2048), norm with qnw (all 16 heads);
// square 8x8 per-XCD chunks over the 16x32 tile grid (R15).
// blocks 512..767: xkv = sbKV @ wkvT^T (N=1024): n0<512 -> K head (norm knw),
// n0>=512 -> V (no norm); row-chunk swizzle kept (B2 only 4 MB total).
// 768 blocks = exactly 3/CU, co-resident.
__global__ __launch_bounds__(256) void gemm12(const bf16* __restrict__ A1,
                                              const bf16* __restrict__ B1,
                                              bf16* __restrict__ C1,
                                              const bf16* __restrict__ A2,
                                              const bf16* __restrict__ B2,
                                              bf16* __restrict__ C2,
                                              const float* __restrict__ qnw,
                                              const float* __restrict__ knw) {
    __shared__ bf16 As[2][128][32];
    __shared__ bf16 Bs[2][128][32];
    const int bid = blockIdx.x;
    if (bid < 512) {
        const int x = bid & 7, c = bid >> 3;     // XCD, chunk id 0..63
        const int bx = ((x & 1) << 3) + (c & 7);
        const int by = ((x >> 1) << 3) + (c >> 3);
        gemm_block<bf16, true>(A1, B1, C1, 2048, 2048, by * 128, bx * 128, As, Bs, qnw);
    } else {
        const int sub = bid - 512;
        const int swz = (sub & 7) * 32 + (sub >> 3);
        const int bx = swz % 8, by = swz / 8;
        const int n0 = bx * 128;
        if (n0 < 512)
            gemm_block<bf16, true>(A2, B2, C2, 1024, 2048, by * 128, n0, As, Bs, knw);
        else
            gemm_block<bf16, false>(A2, B2, C2, 1024, 2048, by * 128, n0, As, Bs, nullptr);
    }
}

// ---------------------------------------------------------------------------
// post_merged: blocks 0..4095 transpose wo -> woT (into wqT buffer, free
// after gemm12); blocks 4096..4351 repack K and V^T (xkv already normed).
__global__ __launch_bounds__(256) void post_merged(const float* __restrict__ wo,
                                                   bf16* __restrict__ woT,
                                                   const bf16* __restrict__ xkv,
                                                   bf16* __restrict__ kf,
                                                   bf16* __restrict__ vf) {
    __shared__ bf16 Vls[64][136];
    int bid = blockIdx.x;
    if (bid < 4096) {
        transpose_flat(wo, woT, 2048, 2048, bid & 63, bid >> 6);
        return;
    }
    int rb = bid - 4096;               // 0..255
    int kt = rb & 31, kvh = (rb >> 5) & 3, b = rb >> 7;
    int tid = threadIdx.x, lane = tid & 63;
    int lrow = lane & 15, quad = lane >> 4;

    // ---- K part (no LDS) ----
    {
        int ks = tid >> 6;
        const bf16* src = xkv + ((long)b * SEQ + kt * 64) * 1024 + kvh * HD;
        bf16* dst = kf + ((long)((b * NKVH + kvh) * 32 + kt)) * 8192;
#pragma unroll
        for (int nt = 0; nt < 4; ++nt) {
            bf16x8 v = *(const bf16x8*)(src + (long)(nt * 16 + lrow) * 1024 + ks * 32 + quad * 8);
            *(bf16x8*)(dst + ((nt * 4 + ks) * 64 + lane) * 8) = v;
        }
    }

    // ---- V part (transpose via LDS) ----
    {
        const bf16* src = xkv + ((long)b * SEQ + kt * 64) * 1024 + 512 + kvh * HD;
#pragma unroll
        for (int p = 0; p < 4; ++p) {
            int c = p * 256 + tid;
            int r = c >> 4, dc = (c & 15) * 8;
            *(uint4*)(&Vls[r][dc]) = *(const uint4*)(src + (long)r * 1024 + dc);
        }
        __syncthreads();
        int w = tid >> 6;
        bf16* dst = vf + ((long)((b * NKVH + kvh) * 32 + kt)) * 8192;
#pragma unroll
        for (int nt = 0; nt < 4; ++nt)
#pragma unroll
            for (int dtl = 0; dtl < 2; ++dtl) {
                int dt = w * 2 + dtl;
                bf16x4 v = {Vls[nt * 16 + quad * 4 + 0][dt * 16 + lrow],
                            Vls[nt * 16 + quad * 4 + 1][dt * 16 + lrow],
                            Vls[nt * 16 + quad * 4 + 2][dt * 16 + lrow],
                            Vls[nt * 16 + quad * 4 + 3][dt * 16 + lrow]};
                *(bf16x4*)(dst + ((nt * 8 + dt) * 64 + lane) * 4) = v;
            }
    }
}

// ---------------------------------------------------------------------------
// Flash attention: R6 structure FROZEN (best measured: ~70 us, VGPR 52).
__global__ __launch_bounds__(512, 4) void attn_kernel(const bf16* __restrict__ Q,
                                                      const bf16* __restrict__ KF,
                                                      const bf16* __restrict__ VF,
                                                      bf16* __restrict__ O) {
    __shared__ bf16 Kf[2][8192];   // [buf][half(2)·nt(2)·ks(4)·512] — 32 KB
    __shared__ bf16 Vf[2][8192];   // [buf][half(2)·nt(2)·dt(8)·256] — 32 KB
    const int tid = threadIdx.x, wave = tid >> 6, lane = tid & 63;
    const int w4 = wave & 3, grpW = wave >> 2;
    const int bid = blockIdx.x;
    const int grp = bid & 7;                  // -> XCD via bid%8 round-robin
    const int b = grp >> 2, kvh = grp & 3;
    const int slot = bid >> 3;                // 0..63
    const int pr = slot & 15;
    const int h = kvh * 4 + (slot >> 4);
    const int lrow = lane & 15, quad = lane >> 4;
    const float scl2 = 0.12751744f;     // (1/sqrt(128)) * log2(e)
    const float THR = 62.7f;            // ~8 ln-units in raw-score domain

    const int qt1 = 31 - pr, qt2 = pr;

    const bf16* kfb = KF + ((long)(b * NKVH + kvh) * 32) * 8192;
    const bf16* vfb = VF + ((long)(b * NKVH + kvh) * 32) * 8192;

    auto stage = [&](int pair, int bsel) {
        const bf16* kg = kfb + (long)pair * 8192 + tid * 8;
        const bf16* vg = vfb + (long)pair * 8192 + tid * 8;
        bf16* kd = &Kf[bsel][0] + tid * 8;
        bf16* vd = &Vf[bsel][0] + tid * 8;
        load_lds16(kg, kd);
        load_lds16(kg + 4096, kd + 4096);
        load_lds16(vg, vd);
        load_lds16(vg + 4096, vd + 4096);
    };

    float m_i = NEG, l_i = 0.f;
    f32x4 oT[8] = {};   // out^T: d = dt*16 + quad*4 + r, q = lane&15
    bf16x8 bqw[4];

    auto combine_write_reset = [&](int qrow) {
        float a1keep = 0.f;
        float* vs = (float*)&Vf[0][0];
        const int sl = w4 * 64 + lane;
        __syncthreads();
        if (grpW == 1) {
            float* d = vs + sl * 18;
#pragma unroll
            for (int dt = 0; dt < 4; ++dt)
#pragma unroll
                for (int r = 0; r < 4; ++r) d[dt * 4 + r] = oT[dt][r];
            d[16] = m_i; d[17] = l_i;
        }
        __syncthreads();
        if (grpW == 0) {
            const float* s = vs + sl * 18;
            float m1 = s[16], l1 = s[17];
            float ms = fmaxf(m_i, m1);
            float a0 = fast_exp2((m_i - ms) * scl2);
            float a1 = fast_exp2((m1 - ms) * scl2);
            a1keep = a1;
            l_i = a0 * l_i + a1 * l1;
#pragma unroll
            for (int dt = 0; dt < 4; ++dt)
#pragma unroll
                for (int r = 0; r < 4; ++r)
                    oT[dt][r] = a0 * oT[dt][r] + a1 * s[dt * 4 + r];
#pragma unroll
            for (int dt = 4; dt < 8; ++dt)
#pragma unroll
                for (int r = 0; r < 4; ++r) oT[dt][r] *= a0;
            m_i = ms;
        }
        __syncthreads();
        if (grpW == 1) {
            float* d = vs + sl * 16;
#pragma unroll
            for (int dt = 4; dt < 8; ++dt)
#pragma unroll
                for (int r = 0; r < 4; ++r) d[(dt - 4) * 4 + r] = oT[dt][r];
        }
        __syncthreads();
        if (grpW == 0) {
            const float* s = vs + sl * 16;
#pragma unroll
            for (int dt = 4; dt < 8; ++dt)
#pragma unroll
                for (int r = 0; r < 4; ++r) oT[dt][r] += a1keep * s[(dt - 4) * 4 + r];
            float inv_l = 1.0f / l_i;
            bf16* obase = O + ((long)(b * SEQ + qrow)) * (NH * HD) + h * HD;
#pragma unroll
            for (int dt = 0; dt < 8; ++dt) {
                bf16x4 o = {(bf16)(oT[dt][0] * inv_l), (bf16)(oT[dt][1] * inv_l),
                            (bf16)(oT[dt][2] * inv_l), (bf16)(oT[dt][3] * inv_l)};
                *(bf16x4*)(obase + dt * 16 + quad * 4) = o;
            }
        }
        __syncthreads();   // scratch/LDS free for restage
        m_i = NEG; l_i = 0.f;
#pragma unroll
        for (int dt = 0; dt < 8; ++dt)
#pragma unroll
            for (int r = 0; r < 4; ++r) oT[dt][r] = 0.f;
    };

    auto process = [&](int i, int itN, int myq, int cur) {
        const int kbg = 2 * i + grpW;
        const bool diag = (i == itN - 1);
        const bf16* kbase = &Kf[cur][0] + grpW * 4096;
        const bf16* vbase = &Vf[cur][0] + grpW * 4096;

        f32x4 st[2];
        __builtin_amdgcn_s_setprio(1);
#pragma unroll
        for (int nt = 0; nt < 2; ++nt) {
            f32x4 acc = {};
#pragma unroll
            for (int ks = 0; ks < 4; ++ks) {
                bf16x8 ak = *(const bf16x8*)(kbase + (nt * 4 + ks) * 512 + lane * 8);
                acc = __builtin_amdgcn_mfma_f32_16x16x32_bf16(ak, bqw[ks], acc, 0, 0, 0);
            }
            st[nt] = acc;
        }
        __builtin_amdgcn_s_setprio(0);
        if (diag) {
#pragma unroll
            for (int nt = 0; nt < 2; ++nt) {
                int kp0 = kbg * 32 + nt * 16 + quad * 4;
#pragma unroll
                for (int r = 0; r < 4; ++r)
                    if (kp0 + r > myq) st[nt][r] = NEG;
            }
        }

        float mx = st[0][0];
#pragma unroll
        for (int nt = 0; nt < 2; ++nt)
#pragma unroll
            for (int r = 0; r < 4; ++r) mx = fmaxf(mx, st[nt][r]);
        mx = fmaxf(mx, __shfl_xor(mx, 16, 64));
        mx = fmaxf(mx, __shfl_xor(mx, 32, 64));

        if (!__all(mx - m_i <= THR)) {
            float mnew = fmaxf(m_i, mx);
            float alpha = fast_exp2((m_i - mnew) * scl2);
            l_i *= alpha;
#pragma unroll
            for (int dt = 0; dt < 8; ++dt)
#pragma unroll
                for (int r = 0; r < 4; ++r) oT[dt][r] *= alpha;
            m_i = mnew;
        }
        float rs = 0.f;
#pragma unroll
        for (int nt = 0; nt < 2; ++nt)
#pragma unroll
            for (int r = 0; r < 4; ++r) {
                float p = fast_exp2((st[nt][r] - m_i) * scl2);
                st[nt][r] = p;
                rs += p;
            }
        rs += __shfl_xor(rs, 16, 64);
        rs += __shfl_xor(rs, 32, 64);
        l_i += rs;

        bf16x4 pf[2];
#pragma unroll
        for (int nt = 0; nt < 2; ++nt) {
            bf16x4 tt = {(bf16)st[nt][0], (bf16)st[nt][1],
                         (bf16)st[nt][2], (bf16)st[nt][3]};
            pf[nt] = tt;
        }

        __builtin_amdgcn_s_setprio(1);
#pragma unroll
        for (int nt = 0; nt < 2; ++nt)
#pragma unroll
            for (int dt = 0; dt < 8; ++dt) {
                bf16x4 av = *(const bf16x4*)(vbase + (nt * 8 + dt) * 256 + lane * 4);
                oT[dt] = mfma_16x16x16(av, pf[nt], oT[dt]);
            }
        __builtin_amdgcn_s_setprio(0);
    };

    // ---- tile 1: qt1, it1 = qt1+1 staged pairs --------------------------
    const int it1 = qt1 + 1;
    const int myq1 = qt1 * 64 + w4 * 16 + lrow;
    {
        const bf16* qrow = Q + ((long)(b * SEQ + myq1)) * (NH * HD) + h * HD;
#pragma unroll
        for (int ks = 0; ks < 4; ++ks)
            bqw[ks] = *(const bf16x8*)(qrow + ks * 32 + quad * 8);
    }
    stage(0, 0);
    __syncthreads();
#pragma unroll 1
    for (int i = 0; i < it1; ++i) {
        const int cur = i & 1;
        if (i + 1 < it1) stage(i + 1, cur ^ 1);
        process(i, it1, myq1, cur);
        __syncthreads();
    }
    combine_write_reset(myq1);

    // ---- tile 2: qt2, it2 = qt2+1 staged pairs --------------------------
    const int it2 = qt2 + 1;
    const int myq2 = qt2 * 64 + w4 * 16 + lrow;
    {
        const bf16* qrow = Q + ((long)(b * SEQ + myq2)) * (NH * HD) + h * HD;
#pragma unroll
        for (int ks = 0; ks < 4; ++ks)
            bqw[ks] = *(const bf16x8*)(qrow + ks * 32 + quad * 8);
    }
    stage(0, 0);
    __syncthreads();
#pragma unroll 1
    for (int i = 0; i < it2; ++i) {
        const int cur = i & 1;
        if (i + 1 < it2) stage(i + 1, cur ^ 1);
        process(i, it2, myq2, cur);
        __syncthreads();
    }
    combine_write_reset(myq2);
}

// ---------------------------------------------------------------------------
extern "C" void kernel_launch(void* const* d_in, const int* in_sizes, int n_in,
                              void* d_out, int out_size, void* d_ws, size_t ws_size,
                              hipStream_t stream) {
    const float* q_stream  = (const float*)d_in[0];
    const float* kv_stream = (const float*)d_in[1];
    const float* wq  = (const float*)d_in[2];
    const float* wk  = (const float*)d_in[3];
    const float* wv  = (const float*)d_in[4];
    const float* wo  = (const float*)d_in[5];
    const float* qnw = (const float*)d_in[6];
    const float* knw = (const float*)d_in[7];
    float* out = (float*)d_out;

    // workspace (bf16 elems), total 30M elems = 60MB
    bf16* ws   = (bf16*)d_ws;
    bf16* sb   = ws;                        // 8M: q bf16, later attn out
    bf16* wqT  = ws + 8L * 1024 * 1024;     // 4M: wq^T, later wo^T
    bf16* wkvT = wqT + 4L * 1024 * 1024;    // 2M: [wk^T ; wv^T] = [1024][2048]
    bf16* xq   = wkvT + 2L * 1024 * 1024;   // 8M: [4096][2048]
    bf16* xkv  = xq + 8L * 1024 * 1024;     // 4M: [4096][1024] = [K | V]
    bf16* kf   = xkv + 4L * 1024 * 1024;    // 2M: K fragment-major
    bf16* vf   = kf + 2L * 1024 * 1024;     // 2M: V^T fragment-major
    // kv bf16 staging lives in d_out (32 MB f32 >= 8 MB needed); the final
    // GEMM fully overwrites out, so scratch use is safe.
    bf16* sbKV = (bf16*)d_out;

    cvt_trans<<<14336, 256, 0, stream>>>(q_stream, kv_stream, sb, sbKV,
                                         wq, wk, wv, wqT, wkvT);
    gemm12<<<768, 256, 0, stream>>>(sb, wqT, xq, sbKV, wkvT, xkv, qnw, knw);
    post_merged<<<4352, 256, 0, stream>>>(wo, wqT, xkv, kf, vf);
    attn_kernel<<<dim3(512), dim3(512), 0, stream>>>(xq, kf, vf, sb);
    gemm3_bt<<<512, 256, 0, stream>>>(sb, wqT, out);

    (void)in_sizes; (void)n_in; (void)out_size; (void)ws_size;
}

// Round 16
// 325.266 us; speedup vs baseline: 1.0344x; 1.0246x over previous
//
#include <hip/hip_runtime.h>
#include <cstdint>

// ---------------------------------------------------------------------------
// JanusCrossAttention: B=2,S=2048, Q_DIM=KV_DIM=2048, H=16, D=128, KVH=4
// I/O fp32; internals bf16 MFMA, fp32 accumulate.
// Pipeline (5 launches), R16 = R13 config restored + gemm3 BK=64:
//   1. cvt_trans: q/kv f32->bf16 + wq/wk/wv transposes
//   2. gemm12: xq + xkv in one 768-block launch (3 blocks/CU, R12-proven),
//      per-head RMSNorm fused into the fp32-accumulator epilogue (R13),
//      row-chunk XCD swizzle (R13 config; R15's square chunk was neutral).
//   3. post_merged: wo transpose + K/V fragment repack
//   4. attn: R6 structure FROZEN (~70 us, VGPR 52)
//   5. gemm3: 128x128 tile, 512 blocks (2/CU, grid-capped), R16: BK=64 as
//      two back-to-back [128][32] k-slices -> 32 barriers instead of 64,
//      32 MFMA/phase. Rationale: at 2/CU there is little cross-block cover
//      for the per-barrier vmcnt(0) drain; halving barrier count attacks
//      that directly. No occupancy cost (grid-capped; 64 KB LDS <= 80).
//      Layout keeps the proven 2-way-free bank pattern and linear
//      global_load_lds destinations (flat [128][64] would be 16-way).
// ---------------------------------------------------------------------------

using bf16 = __bf16;
using bf16x4 = __attribute__((ext_vector_type(4))) __bf16;
using bf16x8 = __attribute__((ext_vector_type(8))) __bf16;
using s16x4  = __attribute__((ext_vector_type(4))) short;
using f32x4  = __attribute__((ext_vector_type(4))) float;

#define SEQ 2048
#define NH 16
#define NKVH 4
#define HD 128

// finite "minus infinity": avoids inf-inf NaNs in the split-K defer-max path
#define NEG (-3.0e38f)

// 16x16x16 bf16 MFMA (K=16) — C layout of a prior 16x16 MFMA feeds B directly.
#if defined(__has_builtin)
#if __has_builtin(__builtin_amdgcn_mfma_f32_16x16x16bf16_1k)
#define HAVE_1K 1
#endif
#endif
__device__ __forceinline__ f32x4 mfma_16x16x16(bf16x4 a, bf16x4 b, f32x4 c) {
#ifdef HAVE_1K
    return __builtin_amdgcn_mfma_f32_16x16x16bf16_1k(
        __builtin_bit_cast(s16x4, a), __builtin_bit_cast(s16x4, b), c, 0, 0, 0);
#else
    f32x4 d;
    asm volatile("v_mfma_f32_16x16x16_bf16 %0, %1, %2, %3"
                 : "=v"(d) : "v"(a), "v"(b), "v"(c));
    return d;
#endif
}

// native exp2 (v_exp_f32)
__device__ __forceinline__ float fast_exp2(float x) {
#if defined(__has_builtin)
#if __has_builtin(__builtin_amdgcn_exp2f)
    return __builtin_amdgcn_exp2f(x);
#else
    return exp2f(x);
#endif
#else
    return exp2f(x);
#endif
}

// async global->LDS, 16B per lane. LDS dest must be wave-uniform base + lane*16.
__device__ __forceinline__ void load_lds16(const bf16* g, bf16* l) {
    __builtin_amdgcn_global_load_lds(
        (const __attribute__((address_space(1))) unsigned int*)g,
        (__attribute__((address_space(3))) unsigned int*)l, 16, 0, 0);
}

// ---------------------------------------------------------------------------
// flat-thread 32x32 transpose tile body: in fp32 [R][C] -> out bf16 [C][R]
__device__ __forceinline__ void transpose_flat(const float* in, bf16* out,
                                               int R, int C, int bx, int by) {
    __shared__ bf16 tile[32][33];
    int tx = threadIdx.x & 31, ty = threadIdx.x >> 5;
    int x  = bx * 32 + tx;
    int y0 = by * 32 + ty;
#pragma unroll
    for (int i = 0; i < 32; i += 8) {
        int y = y0 + i;
        if (y < R && x < C) tile[ty + i][tx] = (bf16)in[(long)y * C + x];
    }
    __syncthreads();
    int ox  = by * 32 + tx;
    int oy0 = bx * 32 + ty;
#pragma unroll
    for (int i = 0; i < 32; i += 8) {
        int oy = oy0 + i;
        if (oy < C && ox < R) out[(long)oy * R + ox] = tile[tx][ty + i];
    }
}

// fused: blocks 0..8191 cvt q/kv f32->bf16; 8192..12287 transpose wq;
// 12288..13311 wk; 13312..14335 wv.
__global__ __launch_bounds__(256) void cvt_trans(const float* __restrict__ q,
                                                 const float* __restrict__ kv,
                                                 bf16* __restrict__ oq,
                                                 bf16* __restrict__ okv,
                                                 const float* __restrict__ wq,
                                                 const float* __restrict__ wk,
                                                 const float* __restrict__ wv,
                                                 bf16* __restrict__ wqT,
                                                 bf16* __restrict__ wkvT) {
    int bid = blockIdx.x;
    if (bid < 8192) {
        int i = bid * 256 + threadIdx.x;
        const float* in;
        bf16* out;
        int j;
        if (i < 1048576) { in = q;  out = oq;  j = i; }
        else             { in = kv; out = okv; j = i - 1048576; }
        const float4* p = (const float4*)in + (long)j * 2;
        float4 f0 = p[0], f1 = p[1];
        bf16x8 o = {(bf16)f0.x, (bf16)f0.y, (bf16)f0.z, (bf16)f0.w,
                    (bf16)f1.x, (bf16)f1.y, (bf16)f1.z, (bf16)f1.w};
        *((bf16x8*)out + j) = o;
    } else if (bid < 12288) {
        int t = bid - 8192;
        transpose_flat(wq, wqT, 2048, 2048, t & 63, t >> 6);
    } else if (bid < 13312) {
        int t = bid - 12288;
        transpose_flat(wk, wkvT, 2048, 512, t & 15, t >> 4);
    } else {
        int t = bid - 13312;
        transpose_flat(wv, wkvT + 512L * 2048, 2048, 512, t & 15, t >> 4);
    }
}

// ---------------------------------------------------------------------------
// Shared GEMM block body: C 128x128 tile at (m0,n0), A[MxK] @ BT[NxK]^T,
// bf16 in, fp32 acc, CT out. Double-buffered global_load_lds staging
// (R9 config — measured best). If NORM: per-head RMSNorm on the fp32
// accumulator before the store (R13; each 128-col tile == one head).
template <typename CT, bool NORM>
__device__ __forceinline__ void gemm_block(const bf16* A, const bf16* BT, CT* C,
                                           int N, int K, int m0, int n0,
                                           bf16 (*As)[128][32], bf16 (*Bs)[128][32],
                                           const float* Wn) {
    const int tid  = threadIdx.x;
    const int wave = tid >> 6, lane = tid & 63;
    const int wm = (wave >> 1) * 64, wn = (wave & 1) * 64;
    const int lrow = lane & 15, quad = lane >> 4;
    const int lko = quad * 8;

    const bf16* ga0 = A  + (long)(m0 + (tid >> 2)) * K + (tid & 3) * 8;
    const bf16* ga1 = ga0 + 64L * K;
    const bf16* gb0 = BT + (long)(n0 + (tid >> 2)) * K + (tid & 3) * 8;
    const bf16* gb1 = gb0 + 64L * K;
    bf16* la0 = &As[0][0][0] + tid * 8;
    bf16* lb0 = &Bs[0][0][0] + tid * 8;

    f32x4 acc[4][4] = {};

    const int nIt = K >> 5;
    load_lds16(ga0, la0);
    load_lds16(ga1, la0 + 2048);
    load_lds16(gb0, lb0);
    load_lds16(gb1, lb0 + 2048);
    __syncthreads();

#pragma unroll 1
    for (int it = 0; it < nIt; ++it) {
        const int cur = it & 1;
        if (it + 1 < nIt) {
            const int k0 = (it + 1) * 32;
            bf16* la = la0 + (cur ^ 1) * 4096;
            bf16* lb = lb0 + (cur ^ 1) * 4096;
            load_lds16(ga0 + k0, la);
            load_lds16(ga1 + k0, la + 2048);
            load_lds16(gb0 + k0, lb);
            load_lds16(gb1 + k0, lb + 2048);
        }
        bf16x8 af[4], bfr[4];
#pragma unroll
        for (int i = 0; i < 4; ++i) af[i]  = *(const bf16x8*)(&As[cur][wm + i * 16 + lrow][lko]);
#pragma unroll
        for (int j = 0; j < 4; ++j) bfr[j] = *(const bf16x8*)(&Bs[cur][wn + j * 16 + lrow][lko]);
#pragma unroll
        for (int i = 0; i < 4; ++i)
#pragma unroll
            for (int j = 0; j < 4; ++j)
                acc[i][j] = __builtin_amdgcn_mfma_f32_16x16x32_bf16(af[i], bfr[j], acc[i][j], 0, 0, 0);
        __syncthreads();
    }

    if constexpr (NORM) {
        float* ssb = (float*)&As[0][0][0];   // [2][128] f32 scratch (1 KB)
#pragma unroll
        for (int i = 0; i < 4; ++i)
#pragma unroll
            for (int r = 0; r < 4; ++r) {
                float p = 0.f;
#pragma unroll
                for (int j = 0; j < 4; ++j) p += acc[i][j][r] * acc[i][j][r];
                p += __shfl_xor(p, 1, 64);
                p += __shfl_xor(p, 2, 64);
                p += __shfl_xor(p, 4, 64);
                p += __shfl_xor(p, 8, 64);
                if (lrow == 0) ssb[(wave & 1) * 128 + wm + i * 16 + quad * 4 + r] = p;
            }
        __syncthreads();
        float wgt[4];
#pragma unroll
        for (int j = 0; j < 4; ++j) wgt[j] = Wn[wn + j * 16 + lrow];
#pragma unroll
        for (int i = 0; i < 4; ++i) {
            const int row0 = wm + i * 16 + quad * 4;
#pragma unroll
            for (int r = 0; r < 4; ++r) {
                float tot = ssb[row0 + r] + ssb[128 + row0 + r];
                float rsc = rsqrtf(tot * (1.0f / 128.0f) + 1e-5f);
#pragma unroll
                for (int j = 0; j < 4; ++j) acc[i][j][r] *= rsc * wgt[j];
            }
        }
    }

#pragma unroll
    for (int i = 0; i < 4; ++i) {
        int mrow0 = m0 + wm + i * 16 + quad * 4;
#pragma unroll
        for (int j = 0; j < 4; ++j) {
            int ncol = n0 + wn + j * 16 + lrow;
#pragma unroll
            for (int r = 0; r < 4; ++r)
                C[(long)(mrow0 + r) * N + ncol] = (CT)acc[i][j][r];
        }
    }
}

// Fused gemm1+gemm2 with in-epilogue RMSNorm (R13 row-chunk swizzle).
// blocks 0..511: xq = sb @ wqT^T (N=2048), norm with qnw (all 16 heads);
// blocks 512..767: xkv = sbKV @ wkvT^T (N=1024): n0<512 -> K head (norm knw),
// n0>=512 -> V (no norm). 768 blocks = exactly 3/CU, co-resident.
__global__ __launch_bounds__(256) void gemm12(const bf16* __restrict__ A1,
                                              const bf16* __restrict__ B1,
                                              bf16* __restrict__ C1,
                                              const bf16* __restrict__ A2,
                                              const bf16* __restrict__ B2,
                                              bf16* __restrict__ C2,
                                              const float* __restrict__ qnw,
                                              const float* __restrict__ knw) {
    __shared__ bf16 As[2][128][32];
    __shared__ bf16 Bs[2][128][32];
    const int bid = blockIdx.x;
    if (bid < 512) {
        const int swz = (bid & 7) * 64 + (bid >> 3);
        const int bx = swz % 16, by = swz / 16;
        gemm_block<bf16, true>(A1, B1, C1, 2048, 2048, by * 128, bx * 128, As, Bs, qnw);
    } else {
        const int sub = bid - 512;
        const int swz = (sub & 7) * 32 + (sub >> 3);
        const int bx = swz % 8, by = swz / 8;
        const int n0 = bx * 128;
        if (n0 < 512)
            gemm_block<bf16, true>(A2, B2, C2, 1024, 2048, by * 128, n0, As, Bs, knw);
        else
            gemm_block<bf16, false>(A2, B2, C2, 1024, 2048, by * 128, n0, As, Bs, nullptr);
    }
}

// ---------------------------------------------------------------------------
// gemm3: out(f32) = ao @ woT^T, 128x128 tiles, 512 blocks, BK=64 (R16).
// K-tile = two back-to-back [128][32] k-slices (same bank-friendly layout,
// linear global_load_lds dests). 32 iterations: 8 staging loads + 32 MFMA
// per barrier — half the drain events of BK=32 at the same occupancy
// (grid-capped 2 blocks/CU; LDS 64 KB <= 80 KB budget). Row-chunk swizzle.
__global__ __launch_bounds__(256) void gemm3_bt(const bf16* __restrict__ A,
                                                const bf16* __restrict__ BT,
                                                float* __restrict__ C) {
    __shared__ bf16 As[2][2][128][32];   // [buf][kslice][row][col] — 32 KB
    __shared__ bf16 Bs[2][2][128][32];   // 32 KB
    const int N = 2048, K = 2048;
    const int tid  = threadIdx.x;
    const int wave = tid >> 6, lane = tid & 63;
    const int bid = blockIdx.x;
    const int swz = (bid & 7) * 64 + (bid >> 3);
    const int bx = swz % 16, by = swz / 16;
    const int m0 = by * 128, n0 = bx * 128;
    const int wm = (wave >> 1) * 64, wn = (wave & 1) * 64;
    const int lrow = lane & 15, quad = lane >> 4;
    const int lko = quad * 8;

    const bf16* ga0 = A  + (long)(m0 + (tid >> 2)) * K + (tid & 3) * 8;
    const bf16* ga1 = ga0 + 64L * K;
    const bf16* gb0 = BT + (long)(n0 + (tid >> 2)) * K + (tid & 3) * 8;
    const bf16* gb1 = gb0 + 64L * K;
    bf16* la0 = &As[0][0][0][0] + tid * 8;
    bf16* lb0 = &Bs[0][0][0][0] + tid * 8;

    // stage K-tile `it` (64 wide, two 32-wide slices) into buffer `buf`
    auto stg = [&](int it, int buf) {
        const int k0 = it * 64;
        bf16* la = la0 + buf * 8192;
        bf16* lb = lb0 + buf * 8192;
        load_lds16(ga0 + k0, la);
        load_lds16(ga1 + k0, la + 2048);
        load_lds16(gb0 + k0, lb);
        load_lds16(gb1 + k0, lb + 2048);
        load_lds16(ga0 + k0 + 32, la + 4096);
        load_lds16(ga1 + k0 + 32, la + 6144);
        load_lds16(gb0 + k0 + 32, lb + 4096);
        load_lds16(gb1 + k0 + 32, lb + 6144);
    };

    f32x4 acc[4][4] = {};
    const int nIt = K >> 6;   // 32
    stg(0, 0);
    __syncthreads();

#pragma unroll 1
    for (int it = 0; it < nIt; ++it) {
        const int cur = it & 1;
        if (it + 1 < nIt) stg(it + 1, cur ^ 1);
#pragma unroll
        for (int ks = 0; ks < 2; ++ks) {
            bf16x8 af[4], bfr[4];
#pragma unroll
            for (int i = 0; i < 4; ++i) af[i]  = *(const bf16x8*)(&As[cur][ks][wm + i * 16 + lrow][lko]);
#pragma unroll
            for (int j = 0; j < 4; ++j) bfr[j] = *(const bf16x8*)(&Bs[cur][ks][wn + j * 16 + lrow][lko]);
#pragma unroll
            for (int i = 0; i < 4; ++i)
#pragma unroll
                for (int j = 0; j < 4; ++j)
                    acc[i][j] = __builtin_amdgcn_mfma_f32_16x16x32_bf16(af[i], bfr[j], acc[i][j], 0, 0, 0);
        }
        __syncthreads();
    }
#pragma unroll
    for (int i = 0; i < 4; ++i) {
        int mrow0 = m0 + wm + i * 16 + quad * 4;
#pragma unroll
        for (int j = 0; j < 4; ++j) {
            int ncol = n0 + wn + j * 16 + lrow;
#pragma unroll
            for (int r = 0; r < 4; ++r)
                C[(long)(mrow0 + r) * N + ncol] = acc[i][j][r];
        }
    }
}

// ---------------------------------------------------------------------------
// post_merged: blocks 0..4095 transpose wo -> woT (into wqT buffer, free
// after gemm12); blocks 4096..4351 repack K and V^T (xkv already normed).
__global__ __launch_bounds__(256) void post_merged(const float* __restrict__ wo,
                                                   bf16* __restrict__ woT,
                                                   const bf16* __restrict__ xkv,
                                                   bf16* __restrict__ kf,
                                                   bf16* __restrict__ vf) {
    __shared__ bf16 Vls[64][136];
    int bid = blockIdx.x;
    if (bid < 4096) {
        transpose_flat(wo, woT, 2048, 2048, bid & 63, bid >> 6);
        return;
    }
    int rb = bid - 4096;               // 0..255
    int kt = rb & 31, kvh = (rb >> 5) & 3, b = rb >> 7;
    int tid = threadIdx.x, lane = tid & 63;
    int lrow = lane & 15, quad = lane >> 4;

    // ---- K part (no LDS) ----
    {
        int ks = tid >> 6;
        const bf16* src = xkv + ((long)b * SEQ + kt * 64) * 1024 + kvh * HD;
        bf16* dst = kf + ((long)((b * NKVH + kvh) * 32 + kt)) * 8192;
#pragma unroll
        for (int nt = 0; nt < 4; ++nt) {
            bf16x8 v = *(const bf16x8*)(src + (long)(nt * 16 + lrow) * 1024 + ks * 32 + quad * 8);
            *(bf16x8*)(dst + ((nt * 4 + ks) * 64 + lane) * 8) = v;
        }
    }

    // ---- V part (transpose via LDS) ----
    {
        const bf16* src = xkv + ((long)b * SEQ + kt * 64) * 1024 + 512 + kvh * HD;
#pragma unroll
        for (int p = 0; p < 4; ++p) {
            int c = p * 256 + tid;
            int r = c >> 4, dc = (c & 15) * 8;
            *(uint4*)(&Vls[r][dc]) = *(const uint4*)(src + (long)r * 1024 + dc);
        }
        __syncthreads();
        int w = tid >> 6;
        bf16* dst = vf + ((long)((b * NKVH + kvh) * 32 + kt)) * 8192;
#pragma unroll
        for (int nt = 0; nt < 4; ++nt)
#pragma unroll
            for (int dtl = 0; dtl < 2; ++dtl) {
                int dt = w * 2 + dtl;
                bf16x4 v = {Vls[nt * 16 + quad * 4 + 0][dt * 16 + lrow],
                            Vls[nt * 16 + quad * 4 + 1][dt * 16 + lrow],
                            Vls[nt * 16 + quad * 4 + 2][dt * 16 + lrow],
                            Vls[nt * 16 + quad * 4 + 3][dt * 16 + lrow]};
                *(bf16x4*)(dst + ((nt * 8 + dt) * 64 + lane) * 4) = v;
            }
    }
}

// ---------------------------------------------------------------------------
// Flash attention: R6 structure FROZEN (best measured: ~70 us, VGPR 52).
__global__ __launch_bounds__(512, 4) void attn_kernel(const bf16* __restrict__ Q,
                                                      const bf16* __restrict__ KF,
                                                      const bf16* __restrict__ VF,
                                                      bf16* __restrict__ O) {
    __shared__ bf16 Kf[2][8192];   // [buf][half(2)·nt(2)·ks(4)·512] — 32 KB
    __shared__ bf16 Vf[2][8192];   // [buf][half(2)·nt(2)·dt(8)·256] — 32 KB
    const int tid = threadIdx.x, wave = tid >> 6, lane = tid & 63;
    const int w4 = wave & 3, grpW = wave >> 2;
    const int bid = blockIdx.x;
    const int grp = bid & 7;                  // -> XCD via bid%8 round-robin
    const int b = grp >> 2, kvh = grp & 3;
    const int slot = bid >> 3;                // 0..63
    const int pr = slot & 15;
    const int h = kvh * 4 + (slot >> 4);
    const int lrow = lane & 15, quad = lane >> 4;
    const float scl2 = 0.12751744f;     // (1/sqrt(128)) * log2(e)
    const float THR = 62.7f;            // ~8 ln-units in raw-score domain

    const int qt1 = 31 - pr, qt2 = pr;

    const bf16* kfb = KF + ((long)(b * NKVH + kvh) * 32) * 8192;
    const bf16* vfb = VF + ((long)(b * NKVH + kvh) * 32) * 8192;

    auto stage = [&](int pair, int bsel) {
        const bf16* kg = kfb + (long)pair * 8192 + tid * 8;
        const bf16* vg = vfb + (long)pair * 8192 + tid * 8;
        bf16* kd = &Kf[bsel][0] + tid * 8;
        bf16* vd = &Vf[bsel][0] + tid * 8;
        load_lds16(kg, kd);
        load_lds16(kg + 4096, kd + 4096);
        load_lds16(vg, vd);
        load_lds16(vg + 4096, vd + 4096);
    };

    float m_i = NEG, l_i = 0.f;
    f32x4 oT[8] = {};   // out^T: d = dt*16 + quad*4 + r, q = lane&15
    bf16x8 bqw[4];

    auto combine_write_reset = [&](int qrow) {
        float a1keep = 0.f;
        float* vs = (float*)&Vf[0][0];
        const int sl = w4 * 64 + lane;
        __syncthreads();
        if (grpW == 1) {
            float* d = vs + sl * 18;
#pragma unroll
            for (int dt = 0; dt < 4; ++dt)
#pragma unroll
                for (int r = 0; r < 4; ++r) d[dt * 4 + r] = oT[dt][r];
            d[16] = m_i; d[17] = l_i;
        }
        __syncthreads();
        if (grpW == 0) {
            const float* s = vs + sl * 18;
            float m1 = s[16], l1 = s[17];
            float ms = fmaxf(m_i, m1);
            float a0 = fast_exp2((m_i - ms) * scl2);
            float a1 = fast_exp2((m1 - ms) * scl2);
            a1keep = a1;
            l_i = a0 * l_i + a1 * l1;
#pragma unroll
            for (int dt = 0; dt < 4; ++dt)
#pragma unroll
                for (int r = 0; r < 4; ++r)
                    oT[dt][r] = a0 * oT[dt][r] + a1 * s[dt * 4 + r];
#pragma unroll
            for (int dt = 4; dt < 8; ++dt)
#pragma unroll
                for (int r = 0; r < 4; ++r) oT[dt][r] *= a0;
            m_i = ms;
        }
        __syncthreads();
        if (grpW == 1) {
            float* d = vs + sl * 16;
#pragma unroll
            for (int dt = 4; dt < 8; ++dt)
#pragma unroll
                for (int r = 0; r < 4; ++r) d[(dt - 4) * 4 + r] = oT[dt][r];
        }
        __syncthreads();
        if (grpW == 0) {
            const float* s = vs + sl * 16;
#pragma unroll
            for (int dt = 4; dt < 8; ++dt)
#pragma unroll
                for (int r = 0; r < 4; ++r) oT[dt][r] += a1keep * s[(dt - 4) * 4 + r];
            float inv_l = 1.0f / l_i;
            bf16* obase = O + ((long)(b * SEQ + qrow)) * (NH * HD) + h * HD;
#pragma unroll
            for (int dt = 0; dt < 8; ++dt) {
                bf16x4 o = {(bf16)(oT[dt][0] * inv_l), (bf16)(oT[dt][1] * inv_l),
                            (bf16)(oT[dt][2] * inv_l), (bf16)(oT[dt][3] * inv_l)};
                *(bf16x4*)(obase + dt * 16 + quad * 4) = o;
            }
        }
        __syncthreads();   // scratch/LDS free for restage
        m_i = NEG; l_i = 0.f;
#pragma unroll
        for (int dt = 0; dt < 8; ++dt)
#pragma unroll
            for (int r = 0; r < 4; ++r) oT[dt][r] = 0.f;
    };

    auto process = [&](int i, int itN, int myq, int cur) {
        const int kbg = 2 * i + grpW;
        const bool diag = (i == itN - 1);
        const bf16* kbase = &Kf[cur][0] + grpW * 4096;
        const bf16* vbase = &Vf[cur][0] + grpW * 4096;

        f32x4 st[2];
        __builtin_amdgcn_s_setprio(1);
#pragma unroll
        for (int nt = 0; nt < 2; ++nt) {
            f32x4 acc = {};
#pragma unroll
            for (int ks = 0; ks < 4; ++ks) {
                bf16x8 ak = *(const bf16x8*)(kbase + (nt * 4 + ks) * 512 + lane * 8);
                acc = __builtin_amdgcn_mfma_f32_16x16x32_bf16(ak, bqw[ks], acc, 0, 0, 0);
            }
            st[nt] = acc;
        }
        __builtin_amdgcn_s_setprio(0);
        if (diag) {
#pragma unroll
            for (int nt = 0; nt < 2; ++nt) {
                int kp0 = kbg * 32 + nt * 16 + quad * 4;
#pragma unroll
                for (int r = 0; r < 4; ++r)
                    if (kp0 + r > myq) st[nt][r] = NEG;
            }
        }

        float mx = st[0][0];
#pragma unroll
        for (int nt = 0; nt < 2; ++nt)
#pragma unroll
            for (int r = 0; r < 4; ++r) mx = fmaxf(mx, st[nt][r]);
        mx = fmaxf(mx, __shfl_xor(mx, 16, 64));
        mx = fmaxf(mx, __shfl_xor(mx, 32, 64));

        if (!__all(mx - m_i <= THR)) {
            float mnew = fmaxf(m_i, mx);
            float alpha = fast_exp2((m_i - mnew) * scl2);
            l_i *= alpha;
#pragma unroll
            for (int dt = 0; dt < 8; ++dt)
#pragma unroll
                for (int r = 0; r < 4; ++r) oT[dt][r] *= alpha;
            m_i = mnew;
        }
        float rs = 0.f;
#pragma unroll
        for (int nt = 0; nt < 2; ++nt)
#pragma unroll
            for (int r = 0; r < 4; ++r) {
                float p = fast_exp2((st[nt][r] - m_i) * scl2);
                st[nt][r] = p;
                rs += p;
            }
        rs += __shfl_xor(rs, 16, 64);
        rs += __shfl_xor(rs, 32, 64);
        l_i += rs;

        bf16x4 pf[2];
#pragma unroll
        for (int nt = 0; nt < 2; ++nt) {
            bf16x4 tt = {(bf16)st[nt][0], (bf16)st[nt][1],
                         (bf16)st[nt][2], (bf16)st[nt][3]};
            pf[nt] = tt;
        }

        __builtin_amdgcn_s_setprio(1);
#pragma unroll
        for (int nt = 0; nt < 2; ++nt)
#pragma unroll
            for (int dt = 0; dt < 8; ++dt) {
                bf16x4 av = *(const bf16x4*)(vbase + (nt * 8 + dt) * 256 + lane * 4);
                oT[dt] = mfma_16x16x16(av, pf[nt], oT[dt]);
            }
        __builtin_amdgcn_s_setprio(0);
    };

    // ---- tile 1: qt1, it1 = qt1+1 staged pairs --------------------------
    const int it1 = qt1 + 1;
    const int myq1 = qt1 * 64 + w4 * 16 + lrow;
    {
        const bf16* qrow = Q + ((long)(b * SEQ + myq1)) * (NH * HD) + h * HD;
#pragma unroll
        for (int ks = 0; ks < 4; ++ks)
            bqw[ks] = *(const bf16x8*)(qrow + ks * 32 + quad * 8);
    }
    stage(0, 0);
    __syncthreads();
#pragma unroll 1
    for (int i = 0; i < it1; ++i) {
        const int cur = i & 1;
        if (i + 1 < it1) stage(i + 1, cur ^ 1);
        process(i, it1, myq1, cur);
        __syncthreads();
    }
    combine_write_reset(myq1);

    // ---- tile 2: qt2, it2 = qt2+1 staged pairs --------------------------
    const int it2 = qt2 + 1;
    const int myq2 = qt2 * 64 + w4 * 16 + lrow;
    {
        const bf16* qrow = Q + ((long)(b * SEQ + myq2)) * (NH * HD) + h * HD;
#pragma unroll
        for (int ks = 0; ks < 4; ++ks)
            bqw[ks] = *(const bf16x8*)(qrow + ks * 32 + quad * 8);
    }
    stage(0, 0);
    __syncthreads();
#pragma unroll 1
    for (int i = 0; i < it2; ++i) {
        const int cur = i & 1;
        if (i + 1 < it2) stage(i + 1, cur ^ 1);
        process(i, it2, myq2, cur);
        __syncthreads();
    }
    combine_write_reset(myq2);
}

// ---------------------------------------------------------------------------
extern "C" void kernel_launch(void* const* d_in, const int* in_sizes, int n_in,
                              void* d_out, int out_size, void* d_ws, size_t ws_size,
                              hipStream_t stream) {
    const float* q_stream  = (const float*)d_in[0];
    const float* kv_stream = (const float*)d_in[1];
    const float* wq  = (const float*)d_in[2];
    const float* wk  = (const float*)d_in[3];
    const float* wv  = (const float*)d_in[4];
    const float* wo  = (const float*)d_in[5];
    const float* qnw = (const float*)d_in[6];
    const float* knw = (const float*)d_in[7];
    float* out = (float*)d_out;

    // workspace (bf16 elems), total 30M elems = 60MB
    bf16* ws   = (bf16*)d_ws;
    bf16* sb   = ws;                        // 8M: q bf16, later attn out
    bf16* wqT  = ws + 8L * 1024 * 1024;     // 4M: wq^T, later wo^T
    bf16* wkvT = wqT + 4L * 1024 * 1024;    // 2M: [wk^T ; wv^T] = [1024][2048]
    bf16* xq   = wkvT + 2L * 1024 * 1024;   // 8M: [4096][2048]
    bf16* xkv  = xq + 8L * 1024 * 1024;     // 4M: [4096][1024] = [K | V]
    bf16* kf   = xkv + 4L * 1024 * 1024;    // 2M: K fragment-major
    bf16* vf   = kf + 2L * 1024 * 1024;     // 2M: V^T fragment-major
    // kv bf16 staging lives in d_out (32 MB f32 >= 8 MB needed); the final
    // GEMM fully overwrites out, so scratch use is safe.
    bf16* sbKV = (bf16*)d_out;

    cvt_trans<<<14336, 256, 0, stream>>>(q_stream, kv_stream, sb, sbKV,
                                         wq, wk, wv, wqT, wkvT);
    gemm12<<<768, 256, 0, stream>>>(sb, wqT, xq, sbKV, wkvT, xkv, qnw, knw);
    post_merged<<<4352, 256, 0, stream>>>(wo, wqT, xkv, kf, vf);
    attn_kernel<<<dim3(512), dim3(512), 0, stream>>>(xq, kf, vf, sb);
    gemm3_bt<<<512, 256, 0, stream>>>(sb, wqT, out);

    (void)in_sizes; (void)n_in; (void)out_size; (void)ws_size;
}

// Round 18
// 319.875 us; speedup vs baseline: 1.0518x; 1.0169x over previous
//
#include <hip/hip_runtime.h>
#include <cstdint>

// ---------------------------------------------------------------------------
// JanusCrossAttention: B=2,S=2048, Q_DIM=KV_DIM=2048, H=16, D=128, KVH=4
// I/O fp32; internals bf16 MFMA, fp32 accumulate.
// Pipeline (5 launches), R17 = R16 + direct kf/vf write from gemm12:
//   1. cvt_trans: q/kv f32->bf16 + wq/wk/wv transposes
//   2. gemm12: xq + K/V in one 768-block launch (3 blocks/CU), RMSNorm fused
//      (R13). R17: K/V blocks write fragment-major kf/vf DIRECTLY from the
//      fp32 accumulator (index maps derived from repack_k/repack_v; V-side
//      is a perfect lane-match -> 16 wide 8B stores; K-side same store count
//      as before). xkv buffer + repack pass eliminated (-24 MB traffic).
//   3. post_merged: wo transpose only
//   4. attn: R6 structure FROZEN (~70 us, VGPR 52)
//   5. gemm3: 128x128, 512 blocks, BK=64 (R16: halved barrier drains at the
//      grid-capped 2 blocks/CU; worked, -8 us)
// (R17 resubmission: previous bench attempt died to an infra container
//  failure before running; kernel unchanged. OOB audit: max kf/vf index
//  2097151 < 2097152; workspace 52 MB <= 60 MB.)
// ---------------------------------------------------------------------------

using bf16 = __bf16;
using bf16x4 = __attribute__((ext_vector_type(4))) __bf16;
using bf16x8 = __attribute__((ext_vector_type(8))) __bf16;
using s16x4  = __attribute__((ext_vector_type(4))) short;
using f32x4  = __attribute__((ext_vector_type(4))) float;

#define SEQ 2048
#define NH 16
#define NKVH 4
#define HD 128

// finite "minus infinity": avoids inf-inf NaNs in the split-K defer-max path
#define NEG (-3.0e38f)

// 16x16x16 bf16 MFMA (K=16) — C layout of a prior 16x16 MFMA feeds B directly.
#if defined(__has_builtin)
#if __has_builtin(__builtin_amdgcn_mfma_f32_16x16x16bf16_1k)
#define HAVE_1K 1
#endif
#endif
__device__ __forceinline__ f32x4 mfma_16x16x16(bf16x4 a, bf16x4 b, f32x4 c) {
#ifdef HAVE_1K
    return __builtin_amdgcn_mfma_f32_16x16x16bf16_1k(
        __builtin_bit_cast(s16x4, a), __builtin_bit_cast(s16x4, b), c, 0, 0, 0);
#else
    f32x4 d;
    asm volatile("v_mfma_f32_16x16x16_bf16 %0, %1, %2, %3"
                 : "=v"(d) : "v"(a), "v"(b), "v"(c));
    return d;
#endif
}

// native exp2 (v_exp_f32)
__device__ __forceinline__ float fast_exp2(float x) {
#if defined(__has_builtin)
#if __has_builtin(__builtin_amdgcn_exp2f)
    return __builtin_amdgcn_exp2f(x);
#else
    return exp2f(x);
#endif
#else
    return exp2f(x);
#endif
}

// async global->LDS, 16B per lane. LDS dest must be wave-uniform base + lane*16.
__device__ __forceinline__ void load_lds16(const bf16* g, bf16* l) {
    __builtin_amdgcn_global_load_lds(
        (const __attribute__((address_space(1))) unsigned int*)g,
        (__attribute__((address_space(3))) unsigned int*)l, 16, 0, 0);
}

// ---------------------------------------------------------------------------
// flat-thread 32x32 transpose tile body: in fp32 [R][C] -> out bf16 [C][R]
__device__ __forceinline__ void transpose_flat(const float* in, bf16* out,
                                               int R, int C, int bx, int by) {
    __shared__ bf16 tile[32][33];
    int tx = threadIdx.x & 31, ty = threadIdx.x >> 5;
    int x  = bx * 32 + tx;
    int y0 = by * 32 + ty;
#pragma unroll
    for (int i = 0; i < 32; i += 8) {
        int y = y0 + i;
        if (y < R && x < C) tile[ty + i][tx] = (bf16)in[(long)y * C + x];
    }
    __syncthreads();
    int ox  = by * 32 + tx;
    int oy0 = bx * 32 + ty;
#pragma unroll
    for (int i = 0; i < 32; i += 8) {
        int oy = oy0 + i;
        if (oy < C && ox < R) out[(long)oy * R + ox] = tile[tx][ty + i];
    }
}

// fused: blocks 0..8191 cvt q/kv f32->bf16; 8192..12287 transpose wq;
// 12288..13311 wk; 13312..14335 wv.
__global__ __launch_bounds__(256) void cvt_trans(const float* __restrict__ q,
                                                 const float* __restrict__ kv,
                                                 bf16* __restrict__ oq,
                                                 bf16* __restrict__ okv,
                                                 const float* __restrict__ wq,
                                                 const float* __restrict__ wk,
                                                 const float* __restrict__ wv,
                                                 bf16* __restrict__ wqT,
                                                 bf16* __restrict__ wkvT) {
    int bid = blockIdx.x;
    if (bid < 8192) {
        int i = bid * 256 + threadIdx.x;
        const float* in;
        bf16* out;
        int j;
        if (i < 1048576) { in = q;  out = oq;  j = i; }
        else             { in = kv; out = okv; j = i - 1048576; }
        const float4* p = (const float4*)in + (long)j * 2;
        float4 f0 = p[0], f1 = p[1];
        bf16x8 o = {(bf16)f0.x, (bf16)f0.y, (bf16)f0.z, (bf16)f0.w,
                    (bf16)f1.x, (bf16)f1.y, (bf16)f1.z, (bf16)f1.w};
        *((bf16x8*)out + j) = o;
    } else if (bid < 12288) {
        int t = bid - 8192;
        transpose_flat(wq, wqT, 2048, 2048, t & 63, t >> 6);
    } else if (bid < 13312) {
        int t = bid - 12288;
        transpose_flat(wk, wkvT, 2048, 512, t & 15, t >> 4);
    } else {
        int t = bid - 13312;
        transpose_flat(wv, wkvT + 512L * 2048, 2048, 512, t & 15, t >> 4);
    }
}

// ---------------------------------------------------------------------------
// Shared GEMM block body: C 128x128 tile at (m0,n0), A[MxK] @ BT[NxK]^T,
// bf16 in, fp32 acc. Double-buffered global_load_lds staging (R9 config).
// NORM: per-head RMSNorm on the fp32 accumulator before the store (R13).
// MODE: 0 = plain row-major CT store; 1 = kf fragment-major direct write;
//       2 = vf fragment-major direct write (R17 — index maps verified
//       against repack_k/repack_v semantics; see store sections).
template <typename CT, bool NORM, int MODE>
__device__ __forceinline__ void gemm_block(const bf16* A, const bf16* BT, CT* C,
                                           int N, int K, int m0, int n0,
                                           bf16 (*As)[128][32], bf16 (*Bs)[128][32],
                                           const float* Wn) {
    const int tid  = threadIdx.x;
    const int wave = tid >> 6, lane = tid & 63;
    const int wm = (wave >> 1) * 64, wn = (wave & 1) * 64;
    const int lrow = lane & 15, quad = lane >> 4;
    const int lko = quad * 8;

    const bf16* ga0 = A  + (long)(m0 + (tid >> 2)) * K + (tid & 3) * 8;
    const bf16* ga1 = ga0 + 64L * K;
    const bf16* gb0 = BT + (long)(n0 + (tid >> 2)) * K + (tid & 3) * 8;
    const bf16* gb1 = gb0 + 64L * K;
    bf16* la0 = &As[0][0][0] + tid * 8;
    bf16* lb0 = &Bs[0][0][0] + tid * 8;

    f32x4 acc[4][4] = {};

    const int nIt = K >> 5;
    load_lds16(ga0, la0);
    load_lds16(ga1, la0 + 2048);
    load_lds16(gb0, lb0);
    load_lds16(gb1, lb0 + 2048);
    __syncthreads();

#pragma unroll 1
    for (int it = 0; it < nIt; ++it) {
        const int cur = it & 1;
        if (it + 1 < nIt) {
            const int k0 = (it + 1) * 32;
            bf16* la = la0 + (cur ^ 1) * 4096;
            bf16* lb = lb0 + (cur ^ 1) * 4096;
            load_lds16(ga0 + k0, la);
            load_lds16(ga1 + k0, la + 2048);
            load_lds16(gb0 + k0, lb);
            load_lds16(gb1 + k0, lb + 2048);
        }
        bf16x8 af[4], bfr[4];
#pragma unroll
        for (int i = 0; i < 4; ++i) af[i]  = *(const bf16x8*)(&As[cur][wm + i * 16 + lrow][lko]);
#pragma unroll
        for (int j = 0; j < 4; ++j) bfr[j] = *(const bf16x8*)(&Bs[cur][wn + j * 16 + lrow][lko]);
#pragma unroll
        for (int i = 0; i < 4; ++i)
#pragma unroll
            for (int j = 0; j < 4; ++j)
                acc[i][j] = __builtin_amdgcn_mfma_f32_16x16x32_bf16(af[i], bfr[j], acc[i][j], 0, 0, 0);
        __syncthreads();
    }

    if constexpr (NORM) {
        float* ssb = (float*)&As[0][0][0];   // [2][128] f32 scratch (1 KB)
#pragma unroll
        for (int i = 0; i < 4; ++i)
#pragma unroll
            for (int r = 0; r < 4; ++r) {
                float p = 0.f;
#pragma unroll
                for (int j = 0; j < 4; ++j) p += acc[i][j][r] * acc[i][j][r];
                p += __shfl_xor(p, 1, 64);
                p += __shfl_xor(p, 2, 64);
                p += __shfl_xor(p, 4, 64);
                p += __shfl_xor(p, 8, 64);
                if (lrow == 0) ssb[(wave & 1) * 128 + wm + i * 16 + quad * 4 + r] = p;
            }
        __syncthreads();
        float wgt[4];
#pragma unroll
        for (int j = 0; j < 4; ++j) wgt[j] = Wn[wn + j * 16 + lrow];
#pragma unroll
        for (int i = 0; i < 4; ++i) {
            const int row0 = wm + i * 16 + quad * 4;
#pragma unroll
            for (int r = 0; r < 4; ++r) {
                float tot = ssb[row0 + r] + ssb[128 + row0 + r];
                float rsc = rsqrtf(tot * (1.0f / 128.0f) + 1e-5f);
#pragma unroll
                for (int j = 0; j < 4; ++j) acc[i][j][r] *= rsc * wgt[j];
            }
        }
    }

    if constexpr (MODE == 0) {
#pragma unroll
        for (int i = 0; i < 4; ++i) {
            int mrow0 = m0 + wm + i * 16 + quad * 4;
#pragma unroll
            for (int j = 0; j < 4; ++j) {
                int ncol = n0 + wn + j * 16 + lrow;
#pragma unroll
                for (int r = 0; r < 4; ++r)
                    C[(long)(mrow0 + r) * N + ncol] = (CT)acc[i][j][r];
            }
        }
    } else if constexpr (MODE == 1) {
        // kf[(b*4+kvh)*32+kt][nt(4)][ks(4)][lane'(64)][8]:
        //   key%64 = nt*16 + (lane'&15), d = ks*32 + (lane'>>4)*8 + jj.
        // acc(i,j,r): key%64 = i*16 + quad*4 + r, d = wn + j*16 + lrow
        //   -> nt=i, lane'&15 = quad*4+r, ks = (wn>>5)+(j>>1),
        //      lane'>>4 = (j&1)*2 + (lrow>>3), jj = lrow&7.
        const int kvh = n0 >> 7, bb = m0 >> 11;
        const int kt = ((m0 & 2047) + wm) >> 6;
        bf16* kfb = (bf16*)C + ((long)((bb * NKVH + kvh) * 32 + kt)) * 8192;
        const int jj = lrow & 7;
#pragma unroll
        for (int i = 0; i < 4; ++i)
#pragma unroll
            for (int j = 0; j < 4; ++j) {
                const int ks = (wn >> 5) + (j >> 1);
                const int lhi = ((j & 1) * 2 + (lrow >> 3)) << 4;
#pragma unroll
                for (int r = 0; r < 4; ++r) {
                    const int lanep = quad * 4 + r + lhi;
                    kfb[((i * 4 + ks) * 64 + lanep) * 8 + jj] = (bf16)acc[i][j][r];
                }
            }
    } else {
        // vf[(b*4+kvh)*32+kt][nt(4)][dt(8)][lane(64)][4]:
        //   d = dt*16 + (lane&15), key%64 = nt*16 + (lane>>4)*4 + jv.
        // acc(i,j,r): key%64 = i*16 + quad*4 + r, d = wn + j*16 + lrow
        //   -> nt=i, dt = wn/16 + j, lane' = lane (exact match), jv = r.
        const int kvh = (n0 - 512) >> 7, bb = m0 >> 11;
        const int kt = ((m0 & 2047) + wm) >> 6;
        bf16* vfb = (bf16*)C + ((long)((bb * NKVH + kvh) * 32 + kt)) * 8192;
        const int dt0 = wn >> 4;
#pragma unroll
        for (int i = 0; i < 4; ++i)
#pragma unroll
            for (int j = 0; j < 4; ++j) {
                bf16x4 v = {(bf16)acc[i][j][0], (bf16)acc[i][j][1],
                            (bf16)acc[i][j][2], (bf16)acc[i][j][3]};
                *(bf16x4*)(vfb + ((i * 8 + dt0 + j) * 64 + lane) * 4) = v;
            }
    }
}

// Fused gemm1+gemm2 with in-epilogue RMSNorm (R13 row-chunk swizzle).
// blocks 0..511: xq = sb @ wqT^T (N=2048), norm qnw, plain store;
// blocks 512..767: K heads (n0<512) -> kf direct write (norm knw);
//                  V heads (n0>=512) -> vf direct write (no norm).
__global__ __launch_bounds__(256) void gemm12(const bf16* __restrict__ A1,
                                              const bf16* __restrict__ B1,
                                              bf16* __restrict__ C1,
                                              const bf16* __restrict__ A2,
                                              const bf16* __restrict__ B2,
                                              bf16* __restrict__ kf,
                                              bf16* __restrict__ vf,
                                              const float* __restrict__ qnw,
                                              const float* __restrict__ knw) {
    __shared__ bf16 As[2][128][32];
    __shared__ bf16 Bs[2][128][32];
    const int bid = blockIdx.x;
    if (bid < 512) {
        const int swz = (bid & 7) * 64 + (bid >> 3);
        const int bx = swz % 16, by = swz / 16;
        gemm_block<bf16, true, 0>(A1, B1, C1, 2048, 2048, by * 128, bx * 128, As, Bs, qnw);
    } else {
        const int sub = bid - 512;
        const int swz = (sub & 7) * 32 + (sub >> 3);
        const int bx = swz % 8, by = swz / 8;
        const int n0 = bx * 128;
        if (n0 < 512)
            gemm_block<bf16, true, 1>(A2, B2, kf, 1024, 2048, by * 128, n0, As, Bs, knw);
        else
            gemm_block<bf16, false, 2>(A2, B2, vf, 1024, 2048, by * 128, n0, As, Bs, nullptr);
    }
}

// ---------------------------------------------------------------------------
// gemm3: out(f32) = ao @ woT^T, 128x128 tiles, 512 blocks, BK=64 (R16).
__global__ __launch_bounds__(256) void gemm3_bt(const bf16* __restrict__ A,
                                                const bf16* __restrict__ BT,
                                                float* __restrict__ C) {
    __shared__ bf16 As[2][2][128][32];   // [buf][kslice][row][col] — 32 KB
    __shared__ bf16 Bs[2][2][128][32];   // 32 KB
    const int N = 2048, K = 2048;
    const int tid  = threadIdx.x;
    const int wave = tid >> 6, lane = tid & 63;
    const int bid = blockIdx.x;
    const int swz = (bid & 7) * 64 + (bid >> 3);
    const int bx = swz % 16, by = swz / 16;
    const int m0 = by * 128, n0 = bx * 128;
    const int wm = (wave >> 1) * 64, wn = (wave & 1) * 64;
    const int lrow = lane & 15, quad = lane >> 4;
    const int lko = quad * 8;

    const bf16* ga0 = A  + (long)(m0 + (tid >> 2)) * K + (tid & 3) * 8;
    const bf16* ga1 = ga0 + 64L * K;
    const bf16* gb0 = BT + (long)(n0 + (tid >> 2)) * K + (tid & 3) * 8;
    const bf16* gb1 = gb0 + 64L * K;
    bf16* la0 = &As[0][0][0][0] + tid * 8;
    bf16* lb0 = &Bs[0][0][0][0] + tid * 8;

    auto stg = [&](int it, int buf) {
        const int k0 = it * 64;
        bf16* la = la0 + buf * 8192;
        bf16* lb = lb0 + buf * 8192;
        load_lds16(ga0 + k0, la);
        load_lds16(ga1 + k0, la + 2048);
        load_lds16(gb0 + k0, lb);
        load_lds16(gb1 + k0, lb + 2048);
        load_lds16(ga0 + k0 + 32, la + 4096);
        load_lds16(ga1 + k0 + 32, la + 6144);
        load_lds16(gb0 + k0 + 32, lb + 4096);
        load_lds16(gb1 + k0 + 32, lb + 6144);
    };

    f32x4 acc[4][4] = {};
    const int nIt = K >> 6;   // 32
    stg(0, 0);
    __syncthreads();

#pragma unroll 1
    for (int it = 0; it < nIt; ++it) {
        const int cur = it & 1;
        if (it + 1 < nIt) stg(it + 1, cur ^ 1);
#pragma unroll
        for (int ks = 0; ks < 2; ++ks) {
            bf16x8 af[4], bfr[4];
#pragma unroll
            for (int i = 0; i < 4; ++i) af[i]  = *(const bf16x8*)(&As[cur][ks][wm + i * 16 + lrow][lko]);
#pragma unroll
            for (int j = 0; j < 4; ++j) bfr[j] = *(const bf16x8*)(&Bs[cur][ks][wn + j * 16 + lrow][lko]);
#pragma unroll
            for (int i = 0; i < 4; ++i)
#pragma unroll
                for (int j = 0; j < 4; ++j)
                    acc[i][j] = __builtin_amdgcn_mfma_f32_16x16x32_bf16(af[i], bfr[j], acc[i][j], 0, 0, 0);
        }
        __syncthreads();
    }
#pragma unroll
    for (int i = 0; i < 4; ++i) {
        int mrow0 = m0 + wm + i * 16 + quad * 4;
#pragma unroll
        for (int j = 0; j < 4; ++j) {
            int ncol = n0 + wn + j * 16 + lrow;
#pragma unroll
            for (int r = 0; r < 4; ++r)
                C[(long)(mrow0 + r) * N + ncol] = acc[i][j][r];
        }
    }
}

// ---------------------------------------------------------------------------
// post_merged: wo transpose only (R17 — repack eliminated; kf/vf now written
// directly by gemm12). woT into wqT buffer (free after gemm12).
__global__ __launch_bounds__(256) void post_merged(const float* __restrict__ wo,
                                                   bf16* __restrict__ woT) {
    int bid = blockIdx.x;
    transpose_flat(wo, woT, 2048, 2048, bid & 63, bid >> 6);
}

// ---------------------------------------------------------------------------
// Flash attention: R6 structure FROZEN (best measured: ~70 us, VGPR 52).
__global__ __launch_bounds__(512, 4) void attn_kernel(const bf16* __restrict__ Q,
                                                      const bf16* __restrict__ KF,
                                                      const bf16* __restrict__ VF,
                                                      bf16* __restrict__ O) {
    __shared__ bf16 Kf[2][8192];   // [buf][half(2)·nt(2)·ks(4)·512] — 32 KB
    __shared__ bf16 Vf[2][8192];   // [buf][half(2)·nt(2)·dt(8)·256] — 32 KB
    const int tid = threadIdx.x, wave = tid >> 6, lane = tid & 63;
    const int w4 = wave & 3, grpW = wave >> 2;
    const int bid = blockIdx.x;
    const int grp = bid & 7;                  // -> XCD via bid%8 round-robin
    const int b = grp >> 2, kvh = grp & 3;
    const int slot = bid >> 3;                // 0..63
    const int pr = slot & 15;
    const int h = kvh * 4 + (slot >> 4);
    const int lrow = lane & 15, quad = lane >> 4;
    const float scl2 = 0.12751744f;     // (1/sqrt(128)) * log2(e)
    const float THR = 62.7f;            // ~8 ln-units in raw-score domain

    const int qt1 = 31 - pr, qt2 = pr;

    const bf16* kfb = KF + ((long)(b * NKVH + kvh) * 32) * 8192;
    const bf16* vfb = VF + ((long)(b * NKVH + kvh) * 32) * 8192;

    auto stage = [&](int pair, int bsel) {
        const bf16* kg = kfb + (long)pair * 8192 + tid * 8;
        const bf16* vg = vfb + (long)pair * 8192 + tid * 8;
        bf16* kd = &Kf[bsel][0] + tid * 8;
        bf16* vd = &Vf[bsel][0] + tid * 8;
        load_lds16(kg, kd);
        load_lds16(kg + 4096, kd + 4096);
        load_lds16(vg, vd);
        load_lds16(vg + 4096, vd + 4096);
    };

    float m_i = NEG, l_i = 0.f;
    f32x4 oT[8] = {};   // out^T: d = dt*16 + quad*4 + r, q = lane&15
    bf16x8 bqw[4];

    auto combine_write_reset = [&](int qrow) {
        float a1keep = 0.f;
        float* vs = (float*)&Vf[0][0];
        const int sl = w4 * 64 + lane;
        __syncthreads();
        if (grpW == 1) {
            float* d = vs + sl * 18;
#pragma unroll
            for (int dt = 0; dt < 4; ++dt)
#pragma unroll
                for (int r = 0; r < 4; ++r) d[dt * 4 + r] = oT[dt][r];
            d[16] = m_i; d[17] = l_i;
        }
        __syncthreads();
        if (grpW == 0) {
            const float* s = vs + sl * 18;
            float m1 = s[16], l1 = s[17];
            float ms = fmaxf(m_i, m1);
            float a0 = fast_exp2((m_i - ms) * scl2);
            float a1 = fast_exp2((m1 - ms) * scl2);
            a1keep = a1;
            l_i = a0 * l_i + a1 * l1;
#pragma unroll
            for (int dt = 0; dt < 4; ++dt)
#pragma unroll
                for (int r = 0; r < 4; ++r)
                    oT[dt][r] = a0 * oT[dt][r] + a1 * s[dt * 4 + r];
#pragma unroll
            for (int dt = 4; dt < 8; ++dt)
#pragma unroll
                for (int r = 0; r < 4; ++r) oT[dt][r] *= a0;
            m_i = ms;
        }
        __syncthreads();
        if (grpW == 1) {
            float* d = vs + sl * 16;
#pragma unroll
            for (int dt = 4; dt < 8; ++dt)
#pragma unroll
                for (int r = 0; r < 4; ++r) d[(dt - 4) * 4 + r] = oT[dt][r];
        }
        __syncthreads();
        if (grpW == 0) {
            const float* s = vs + sl * 16;
#pragma unroll
            for (int dt = 4; dt < 8; ++dt)
#pragma unroll
                for (int r = 0; r < 4; ++r) oT[dt][r] += a1keep * s[(dt - 4) * 4 + r];
            float inv_l = 1.0f / l_i;
            bf16* obase = O + ((long)(b * SEQ + qrow)) * (NH * HD) + h * HD;
#pragma unroll
            for (int dt = 0; dt < 8; ++dt) {
                bf16x4 o = {(bf16)(oT[dt][0] * inv_l), (bf16)(oT[dt][1] * inv_l),
                            (bf16)(oT[dt][2] * inv_l), (bf16)(oT[dt][3] * inv_l)};
                *(bf16x4*)(obase + dt * 16 + quad * 4) = o;
            }
        }
        __syncthreads();   // scratch/LDS free for restage
        m_i = NEG; l_i = 0.f;
#pragma unroll
        for (int dt = 0; dt < 8; ++dt)
#pragma unroll
            for (int r = 0; r < 4; ++r) oT[dt][r] = 0.f;
    };

    auto process = [&](int i, int itN, int myq, int cur) {
        const int kbg = 2 * i + grpW;
        const bool diag = (i == itN - 1);
        const bf16* kbase = &Kf[cur][0] + grpW * 4096;
        const bf16* vbase = &Vf[cur][0] + grpW * 4096;

        f32x4 st[2];
        __builtin_amdgcn_s_setprio(1);
#pragma unroll
        for (int nt = 0; nt < 2; ++nt) {
            f32x4 acc = {};
#pragma unroll
            for (int ks = 0; ks < 4; ++ks) {
                bf16x8 ak = *(const bf16x8*)(kbase + (nt * 4 + ks) * 512 + lane * 8);
                acc = __builtin_amdgcn_mfma_f32_16x16x32_bf16(ak, bqw[ks], acc, 0, 0, 0);
            }
            st[nt] = acc;
        }
        __builtin_amdgcn_s_setprio(0);
        if (diag) {
#pragma unroll
            for (int nt = 0; nt < 2; ++nt) {
                int kp0 = kbg * 32 + nt * 16 + quad * 4;
#pragma unroll
                for (int r = 0; r < 4; ++r)
                    if (kp0 + r > myq) st[nt][r] = NEG;
            }
        }

        float mx = st[0][0];
#pragma unroll
        for (int nt = 0; nt < 2; ++nt)
#pragma unroll
            for (int r = 0; r < 4; ++r) mx = fmaxf(mx, st[nt][r]);
        mx = fmaxf(mx, __shfl_xor(mx, 16, 64));
        mx = fmaxf(mx, __shfl_xor(mx, 32, 64));

        if (!__all(mx - m_i <= THR)) {
            float mnew = fmaxf(m_i, mx);
            float alpha = fast_exp2((m_i - mnew) * scl2);
            l_i *= alpha;
#pragma unroll
            for (int dt = 0; dt < 8; ++dt)
#pragma unroll
                for (int r = 0; r < 4; ++r) oT[dt][r] *= alpha;
            m_i = mnew;
        }
        float rs = 0.f;
#pragma unroll
        for (int nt = 0; nt < 2; ++nt)
#pragma unroll
            for (int r = 0; r < 4; ++r) {
                float p = fast_exp2((st[nt][r] - m_i) * scl2);
                st[nt][r] = p;
                rs += p;
            }
        rs += __shfl_xor(rs, 16, 64);
        rs += __shfl_xor(rs, 32, 64);
        l_i += rs;

        bf16x4 pf[2];
#pragma unroll
        for (int nt = 0; nt < 2; ++nt) {
            bf16x4 tt = {(bf16)st[nt][0], (bf16)st[nt][1],
                         (bf16)st[nt][2], (bf16)st[nt][3]};
            pf[nt] = tt;
        }

        __builtin_amdgcn_s_setprio(1);
#pragma unroll
        for (int nt = 0; nt < 2; ++nt)
#pragma unroll
            for (int dt = 0; dt < 8; ++dt) {
                bf16x4 av = *(const bf16x4*)(vbase + (nt * 8 + dt) * 256 + lane * 4);
                oT[dt] = mfma_16x16x16(av, pf[nt], oT[dt]);
            }
        __builtin_amdgcn_s_setprio(0);
    };

    // ---- tile 1: qt1, it1 = qt1+1 staged pairs --------------------------
    const int it1 = qt1 + 1;
    const int myq1 = qt1 * 64 + w4 * 16 + lrow;
    {
        const bf16* qrow = Q + ((long)(b * SEQ + myq1)) * (NH * HD) + h * HD;
#pragma unroll
        for (int ks = 0; ks < 4; ++ks)
            bqw[ks] = *(const bf16x8*)(qrow + ks * 32 + quad * 8);
    }
    stage(0, 0);
    __syncthreads();
#pragma unroll 1
    for (int i = 0; i < it1; ++i) {
        const int cur = i & 1;
        if (i + 1 < it1) stage(i + 1, cur ^ 1);
        process(i, it1, myq1, cur);
        __syncthreads();
    }
    combine_write_reset(myq1);

    // ---- tile 2: qt2, it2 = qt2+1 staged pairs --------------------------
    const int it2 = qt2 + 1;
    const int myq2 = qt2 * 64 + w4 * 16 + lrow;
    {
        const bf16* qrow = Q + ((long)(b * SEQ + myq2)) * (NH * HD) + h * HD;
#pragma unroll
        for (int ks = 0; ks < 4; ++ks)
            bqw[ks] = *(const bf16x8*)(qrow + ks * 32 + quad * 8);
    }
    stage(0, 0);
    __syncthreads();
#pragma unroll 1
    for (int i = 0; i < it2; ++i) {
        const int cur = i & 1;
        if (i + 1 < it2) stage(i + 1, cur ^ 1);
        process(i, it2, myq2, cur);
        __syncthreads();
    }
    combine_write_reset(myq2);
}

// ---------------------------------------------------------------------------
extern "C" void kernel_launch(void* const* d_in, const int* in_sizes, int n_in,
                              void* d_out, int out_size, void* d_ws, size_t ws_size,
                              hipStream_t stream) {
    const float* q_stream  = (const float*)d_in[0];
    const float* kv_stream = (const float*)d_in[1];
    const float* wq  = (const float*)d_in[2];
    const float* wk  = (const float*)d_in[3];
    const float* wv  = (const float*)d_in[4];
    const float* wo  = (const float*)d_in[5];
    const float* qnw = (const float*)d_in[6];
    const float* knw = (const float*)d_in[7];
    float* out = (float*)d_out;

    // workspace (bf16 elems); xkv slot retired in R17 (kf/vf written directly)
    bf16* ws   = (bf16*)d_ws;
    bf16* sb   = ws;                        // 8M: q bf16, later attn out
    bf16* wqT  = ws + 8L * 1024 * 1024;     // 4M: wq^T, later wo^T
    bf16* wkvT = wqT + 4L * 1024 * 1024;    // 2M: [wk^T ; wv^T] = [1024][2048]
    bf16* xq   = wkvT + 2L * 1024 * 1024;   // 8M: [4096][2048]
    bf16* kf   = xq + 8L * 1024 * 1024;     // 2M: K fragment-major
    bf16* vf   = kf + 2L * 1024 * 1024;     // 2M: V^T fragment-major
    // kv bf16 staging lives in d_out (32 MB f32 >= 8 MB needed); the final
    // GEMM fully overwrites out, so scratch use is safe.
    bf16* sbKV = (bf16*)d_out;

    cvt_trans<<<14336, 256, 0, stream>>>(q_stream, kv_stream, sb, sbKV,
                                         wq, wk, wv, wqT, wkvT);
    gemm12<<<768, 256, 0, stream>>>(sb, wqT, xq, sbKV, wkvT, kf, vf, qnw, knw);
    post_merged<<<4096, 256, 0, stream>>>(wo, wqT);
    attn_kernel<<<dim3(512), dim3(512), 0, stream>>>(xq, kf, vf, sb);
    gemm3_bt<<<512, 256, 0, stream>>>(sb, wqT, out);

    (void)in_sizes; (void)n_in; (void)out_size; (void)ws_size;
}